// Round 9
// baseline (262.370 us; speedup 1.0000x reference)
//
#include <hip/hip_runtime.h>
#include <math.h>

#define D_MODEL 1024
#define NHEADS  16
#define NKV     4
#define HDIM    64
#define KVDIM   256
#define BB      2
#define NN      2048
#define MROWS   (BB*NN)        // 4096
#define QKVN    1536           // 1024 + 256 + 256
#define NTASK   (MROWS*NHEADS) // 65536
#define NSPLIT  4

typedef unsigned short ushort_t;
typedef unsigned int uint_t;
typedef float    f32x4 __attribute__((ext_vector_type(4)));
typedef _Float16 h16x8 __attribute__((ext_vector_type(8)));
typedef __fp16   fp16x2 __attribute__((ext_vector_type(2)));

#define MFMAH(A,B,C) __builtin_amdgcn_mfma_f32_16x16x32_f16((A),(B),(C),0,0,0)

// async global->LDS, 16B per lane; LDS dest = wave-uniform base + lane*16
#define GLDS(gp, lp) __builtin_amdgcn_global_load_lds( \
    (const __attribute__((address_space(1))) void*)(gp), \
    (__attribute__((address_space(3))) void*)(lp), 16, 0, 0)

// fp32 -> f16 scalar
__device__ __forceinline__ ushort_t f2h(float f) {
    _Float16 h = (_Float16)f;
    return *(ushort_t*)&h;
}
// two fp32 -> packed f16x2, single v_cvt_pkrtz_f16_f32
__device__ __forceinline__ uint_t pk2h(float a, float b) {
    fp16x2 v = __builtin_amdgcn_cvt_pkrtz(a, b);
    return *(uint_t*)&v;
}

// ---------------------------------------------------------------------------
// castx: fp32 -> f16, 4 elements/thread
// ---------------------------------------------------------------------------
__global__ __launch_bounds__(256)
void cast_kernel(const float* __restrict__ src, ushort_t* __restrict__ dst, int n4)
{
    int i = blockIdx.x * 256 + threadIdx.x;
    if (i >= n4) return;
    float4 v = ((const float4*)src)[i];
    uint2 o;
    o.x = pk2h(v.x, v.y);
    o.y = pk2h(v.z, v.w);
    ((uint2*)dst)[i] = o;
}

// ---------------------------------------------------------------------------
// transpose + cast: src fp32 [K][N] -> dst f16 [N][K]
// ---------------------------------------------------------------------------
__global__ __launch_bounds__(256)
void transpose_cast(const float* __restrict__ src, ushort_t* __restrict__ dst,
                    int K, int N)
{
    __shared__ float T[32][33];
    const int tx = threadIdx.x & 31, ty = threadIdx.x >> 5;
    const int n0 = blockIdx.x * 32, k0 = blockIdx.y * 32;
#pragma unroll
    for (int i = 0; i < 4; i++)
        T[ty + i * 8][tx] = src[(size_t)(k0 + ty + i * 8) * N + n0 + tx];
    __syncthreads();
#pragma unroll
    for (int i = 0; i < 4; i++)
        dst[(size_t)(n0 + ty + i * 8) * K + k0 + tx] = f2h(T[tx][ty + i * 8]);
}

// ---------------------------------------------------------------------------
// V transpose: QKVf cols [1280,1536) per batch -> Vt f16 [(b*256+d)][2048]
// ---------------------------------------------------------------------------
__global__ __launch_bounds__(256)
void vtrans_kernel(const float* __restrict__ QKVf, ushort_t* __restrict__ Vt)
{
    __shared__ float T[32][33];
    const int tx = threadIdx.x & 31, ty = threadIdx.x >> 5;
    const int n0 = blockIdx.x * 32, d0 = blockIdx.y * 32, b = blockIdx.z;
#pragma unroll
    for (int i = 0; i < 4; i++)
        T[ty + i * 8][tx] =
            QKVf[(size_t)(b * NN + n0 + ty + i * 8) * QKVN + 1280 + d0 + tx];
    __syncthreads();
#pragma unroll
    for (int i = 0; i < 4; i++)
        Vt[(size_t)(b * 256 + d0 + ty + i * 8) * NN + n0 + tx] = f2h(T[tx][ty + i * 8]);
}

// ---------------------------------------------------------------------------
// RoPE + cast(f16) + relayout for Q and K (reads fp32 QKVf).
// Q gets 0.125*log2(e) folded in (softmax runs base-2).
// ---------------------------------------------------------------------------
#define NQW (MROWS*NHEADS*32)   // 2,097,152
#define NKW (MROWS*NKV*32)      //   524,288
__global__ __launch_bounds__(256)
void rope_kernel(const float* __restrict__ QKVf, const float* __restrict__ Cos,
                 const float* __restrict__ Sin, ushort_t* __restrict__ Qb,
                 ushort_t* __restrict__ Kb)
{
    const float SC = 0.125f * 1.44269504f;
    int idx = blockIdx.x * 256 + threadIdx.x;
    if (idx < NQW) {
        const int row = idx >> 9, rem = idx & 511;
        const int h = rem >> 5, j = rem & 31;
        const int b = row >> 11, n = row & (NN - 1);
        const float* s_ = QKVf + (size_t)row * QKVN + h * 64;
        const float e = s_[2 * j], o = s_[2 * j + 1];
        const float c = Cos[n * 32 + j], s = Sin[n * 32 + j];
        ushort_t* dst = Qb + ((size_t)(b * 16 + h) * NN + n) * 64;
        dst[j]      = f2h((e * c - o * s) * SC);
        dst[j + 32] = f2h((e * s + o * c) * SC);
    } else {
        const int i2 = idx - NQW;
        const int row = i2 >> 7, rem = i2 & 127;
        const int h = rem >> 5, j = rem & 31;
        const int b = row >> 11, n = row & (NN - 1);
        const float* s_ = QKVf + (size_t)row * QKVN + 1024 + h * 64;
        const float e = s_[2 * j], o = s_[2 * j + 1];
        const float c = Cos[n * 32 + j], s = Sin[n * 32 + j];
        ushort_t* dst = Kb + ((size_t)(b * 4 + h) * NN + n) * 64;
        dst[j]      = f2h(e * c - o * s);
        dst[j + 32] = f2h(e * s + o * c);
    }
}

// ---------------------------------------------------------------------------
// f16 MFMA GEMM, B^T form, m97-style: global_load_lds width-16 staging into
// UNPADDED [128][32] LDS tiles (layout = exact lane order; frag b128 reads
// land on the 8/bank floor). 128x128 tile, BK=32, 4 waves, 4x4 16x16x32 MFMA.
// ---------------------------------------------------------------------------
__global__ __launch_bounds__(256)
void gemm_bt(const ushort_t* __restrict__ A, const ushort_t* __restrict__ Bt,
             float* __restrict__ C, int M, int N, int K)
{
    __shared__ ushort_t As[128 * 32];
    __shared__ ushort_t Bs[128 * 32];

    const int tid  = threadIdx.x;
    const int wave = tid >> 6, lane = tid & 63;
    const int quad = lane >> 4, l16 = lane & 15;
    const int rowBase = blockIdx.y * 128, colBase = blockIdx.x * 128;
    const int wm = (wave >> 1) * 64, wn = (wave & 1) * 64;

    f32x4 acc[4][4];
    const f32x4 zz = {0.f, 0.f, 0.f, 0.f};
#pragma unroll
    for (int i = 0; i < 4; i++)
#pragma unroll
        for (int j = 0; j < 4; j++) acc[i][j] = zz;

    // staging: wave segment j in {0,1}: rows wave*32 + j*16 + lane/4,
    // cols (lane&3)*8; LDS dest = &As[(wave*2+j)*512] + lane*16B (contiguous)
    const int sr = wave * 32 + (lane >> 2);
    const int sc = (lane & 3) * 8;
    const ushort_t* Ag0 = A  + (size_t)(rowBase + sr) * K + sc;
    const ushort_t* Ag1 = A  + (size_t)(rowBase + sr + 16) * K + sc;
    const ushort_t* Bg0 = Bt + (size_t)(colBase + sr) * K + sc;
    const ushort_t* Bg1 = Bt + (size_t)(colBase + sr + 16) * K + sc;
    ushort_t* Al0 = &As[(wave * 2 + 0) * 512];
    ushort_t* Al1 = &As[(wave * 2 + 1) * 512];
    ushort_t* Bl0 = &Bs[(wave * 2 + 0) * 512];
    ushort_t* Bl1 = &Bs[(wave * 2 + 1) * 512];

    for (int k0 = 0; k0 < K; k0 += 32) {
        __syncthreads();                 // prev-iter frag reads done
        GLDS(Ag0 + k0, Al0);
        GLDS(Ag1 + k0, Al1);
        GLDS(Bg0 + k0, Bl0);
        GLDS(Bg1 + k0, Bl1);
        __syncthreads();                 // drains vmcnt -> LDS valid

        h16x8 af[4], bf[4];
#pragma unroll
        for (int mt = 0; mt < 4; mt++)
            af[mt] = *(const h16x8*)&As[(wm + mt * 16 + l16) * 32 + quad * 8];
#pragma unroll
        for (int nt = 0; nt < 4; nt++)
            bf[nt] = *(const h16x8*)&Bs[(wn + nt * 16 + l16) * 32 + quad * 8];
#pragma unroll
        for (int mt = 0; mt < 4; mt++)
#pragma unroll
            for (int nt = 0; nt < 4; nt++)
                acc[mt][nt] = MFMAH(af[mt], bf[nt], acc[mt][nt]);
    }

#pragma unroll
    for (int mt = 0; mt < 4; mt++)
#pragma unroll
        for (int nt = 0; nt < 4; nt++) {
            const int row = rowBase + wm + mt * 16 + quad * 4;
            const int col = colBase + wn + nt * 16 + l16;
#pragma unroll
            for (int r = 0; r < 4; r++)
                C[(size_t)(row + r) * N + col] = acc[mt][nt][r];
        }
}

// ---------------------------------------------------------------------------
// MFMA flash attention v5: S^T form, f16 operands, mt=4 (wave = 64 q-rows,
// block = 256 q-rows) to amortize K/V LDS frag reads 2x over v4.
// Split-K x4 (512 keys/block, 8 tiles of 64), no-max softmax (order-
// invariant -> rotated key start), P packed to f16 via v_cvt_pkrtz.
// LDS: Ks/Vs 64x72 + per-wave P^T [64 qrows][72] = 54 KB -> 2 blocks/CU.
// ---------------------------------------------------------------------------
__global__ __launch_bounds__(256)
void attn_mfma(const ushort_t* __restrict__ Qb, const ushort_t* __restrict__ Kb,
               const ushort_t* __restrict__ Vt, float* __restrict__ Pnum,
               float* __restrict__ Pl)
{
    const int qt = blockIdx.x, h = blockIdx.y;
    const int b = blockIdx.z >> 2, chunk = blockIdx.z & 3;
    const int kvh = h >> 2;
    const int tid = threadIdx.x;
    const int wave = tid >> 6, lane = tid & 63;
    const int quad = lane >> 4, l16 = lane & 15;

    __shared__ ushort_t Ks[64][72];         // [key][dim]
    __shared__ ushort_t Vs[64][72];         // [dim][key]
    __shared__ ushort_t Ps[4][64 * 72];     // per-wave P^T [qrow(mt*16+l16)][key]
    ushort_t* ps = &Ps[wave][0];

    // ---- Q B-frags: 64 rows per wave (4 m-tiles), resident in registers
    const int row0 = qt * 256 + wave * 64;
    h16x8 qf[4][2];
#pragma unroll
    for (int mt = 0; mt < 4; mt++) {
        const ushort_t* qp =
            Qb + ((size_t)(b * 16 + h) * NN + row0 + mt * 16 + l16) * 64 + quad * 8;
        qf[mt][0] = *(const h16x8*)qp;
        qf[mt][1] = *(const h16x8*)(qp + 32);
    }

    const ushort_t* kbase = Kb + (size_t)(b * 4 + kvh) * NN * 64;
    const ushort_t* vbase = Vt + (size_t)(b * 256 + kvh * 64) * NN;
    const int key_lo = chunk * (NN / NSPLIT);          // 512-key chunk
    const int rot = (qt + ((h & 3) << 1)) & 7;

    const int srow = tid >> 2, sseg = (tid & 3) * 8;

    const f32x4 zz = {0.f, 0.f, 0.f, 0.f};
    f32x4 o[4][4];
#pragma unroll
    for (int mt = 0; mt < 4; mt++)
#pragma unroll
        for (int dt = 0; dt < 4; dt++) o[mt][dt] = zz;
    float lacc[4] = {0.f, 0.f, 0.f, 0.f};

    // prefetch tile 0
    int key0 = key_lo + rot * 64;
    const ushort_t* kp0 = kbase + (size_t)(key0 + srow) * 64 + sseg;
    const ushort_t* vp0 = vbase + (size_t)srow * NN + key0 + sseg;
    uint4 kreg0 = *(const uint4*)kp0;
    uint4 kreg1 = *(const uint4*)(kp0 + 32);
    uint4 vreg0 = *(const uint4*)vp0;
    uint4 vreg1 = *(const uint4*)(vp0 + 32);

    for (int t = 0; t < 8; t++) {
        __syncthreads();
        *(uint4*)&Ks[srow][sseg]      = kreg0;
        *(uint4*)&Ks[srow][sseg + 32] = kreg1;
        *(uint4*)&Vs[srow][sseg]      = vreg0;
        *(uint4*)&Vs[srow][sseg + 32] = vreg1;
        __syncthreads();

        if (t < 7) {
            const int kn = key_lo + ((rot + t + 1) & 7) * 64;
            const ushort_t* kpn = kbase + (size_t)(kn + srow) * 64 + sseg;
            const ushort_t* vpn = vbase + (size_t)srow * NN + kn + sseg;
            kreg0 = *(const uint4*)kpn;
            kreg1 = *(const uint4*)(kpn + 32);
            vreg0 = *(const uint4*)vpn;
            vreg1 = *(const uint4*)(vpn + 32);
        }

        // ---- per kt: S^T = K Q^T for all 4 m-tiles, then exp2+pack to LDS
#pragma unroll
        for (int kt = 0; kt < 4; kt++) {
            h16x8 kf0 = *(const h16x8*)&Ks[kt * 16 + l16][quad * 8];
            h16x8 kf1 = *(const h16x8*)&Ks[kt * 16 + l16][32 + quad * 8];
            f32x4 st[4];
#pragma unroll
            for (int mt = 0; mt < 4; mt++) {
                st[mt] = MFMAH(kf0, qf[mt][0], zz);
                st[mt] = MFMAH(kf1, qf[mt][1], st[mt]);
            }
#pragma unroll
            for (int mt = 0; mt < 4; mt++) {
                const float p0 = exp2f(st[mt][0]);
                const float p1 = exp2f(st[mt][1]);
                const float p2 = exp2f(st[mt][2]);
                const float p3 = exp2f(st[mt][3]);
                lacc[mt] += (p0 + p1) + (p2 + p3);
                uint2 pk;
                pk.x = pk2h(p0, p1);
                pk.y = pk2h(p2, p3);
                *(uint2*)&ps[(mt * 16 + l16) * 72 + kt * 16 + quad * 4] = pk;
            }
        }

        // ---- O^T += V P^T  (V frags read once, shared across all m-tiles)
        h16x8 vf[4][2];
#pragma unroll
        for (int dt = 0; dt < 4; dt++) {
            vf[dt][0] = *(const h16x8*)&Vs[dt * 16 + l16][quad * 8];
            vf[dt][1] = *(const h16x8*)&Vs[dt * 16 + l16][32 + quad * 8];
        }
#pragma unroll
        for (int mt = 0; mt < 4; mt++) {
            h16x8 pa0 = *(const h16x8*)&ps[(mt * 16 + l16) * 72 + quad * 8];
            h16x8 pa1 = *(const h16x8*)&ps[(mt * 16 + l16) * 72 + 32 + quad * 8];
#pragma unroll
            for (int dt = 0; dt < 4; dt++) {
                o[mt][dt] = MFMAH(vf[dt][0], pa0, o[mt][dt]);
                o[mt][dt] = MFMAH(vf[dt][1], pa1, o[mt][dt]);
            }
        }
    }

    // ---- reduce l across the 4 quads — once per kernel
#pragma unroll
    for (int mt = 0; mt < 4; mt++) {
        lacc[mt] += __shfl_xor(lacc[mt], 16, 64);
        lacc[mt] += __shfl_xor(lacc[mt], 32, 64);
    }

    // ---- write unnormalized partials (contiguous float4 stores)
    const size_t task0 = (size_t)(b * 16 + h) * NN + row0;
    float* np = Pnum + ((size_t)chunk * NTASK + task0) * 64;
#pragma unroll
    for (int mt = 0; mt < 4; mt++) {
#pragma unroll
        for (int dt = 0; dt < 4; dt++) {
            f32x4 v = o[mt][dt];
            *(float4*)&np[(size_t)(mt * 16 + l16) * 64 + dt * 16 + quad * 4] =
                make_float4(v[0], v[1], v[2], v[3]);
        }
        if (quad == 0)
            Pl[(size_t)chunk * NTASK + task0 + mt * 16 + l16] = lacc[mt];
    }
}

// ---------------------------------------------------------------------------
// Combine 4 split partials: O = sum(num_s)/sum(l_s), write f16 Ob.
// ---------------------------------------------------------------------------
__global__ __launch_bounds__(256)
void attn_combine(const float* __restrict__ Pnum, const float* __restrict__ Pl,
                  ushort_t* __restrict__ Ob)
{
    const int gid  = blockIdx.x * 256 + threadIdx.x;
    const int task = gid >> 4;
    const int d    = (gid & 15) * 4;
    float4 acc = make_float4(0.f, 0.f, 0.f, 0.f);
    float l = 0.f;
#pragma unroll
    for (int s = 0; s < NSPLIT; s++) {
        const float4 v = *(const float4*)&Pnum[((size_t)s * NTASK + task) * 64 + d];
        acc.x += v.x; acc.y += v.y; acc.z += v.z; acc.w += v.w;
        l += Pl[(size_t)s * NTASK + task];
    }
    const float inv = 1.0f / l;
    const int n = task & (NN - 1), bh = task >> 11;
    const int h = bh & (NHEADS - 1), b = bh >> 4;
    ushort_t* op = Ob + (size_t)(b * NN + n) * D_MODEL + h * 64 + d;
    uint2 o2;
    o2.x = pk2h(acc.x * inv, acc.y * inv);
    o2.y = pk2h(acc.z * inv, acc.w * inv);
    *(uint2*)op = o2;
}

// ---------------------------------------------------------------------------
extern "C" void kernel_launch(void* const* d_in, const int* in_sizes, int n_in,
                              void* d_out, int out_size, void* d_ws, size_t ws_size,
                              hipStream_t stream)
{
    const float* x    = (const float*)d_in[0];
    const float* cosp = (const float*)d_in[1];
    const float* sinp = (const float*)d_in[2];
    const float* Wq   = (const float*)d_in[3];
    const float* Wk   = (const float*)d_in[4];
    const float* Wv   = (const float*)d_in[5];
    const float* Wo   = (const float*)d_in[6];
    float* out = (float*)d_out;

    char* w = (char*)d_ws;
    ushort_t* xb     = (ushort_t*)w;                       w += (size_t)MROWS * D_MODEL * 2;
    ushort_t* WqkvT  = (ushort_t*)w;                       w += (size_t)QKVN * D_MODEL * 2;
    ushort_t* WoT    = (ushort_t*)w;                       w += (size_t)D_MODEL * D_MODEL * 2;
    float*    QKVf   = (float*)w;                          w += (size_t)MROWS * QKVN * 4;
    ushort_t* Qbuf   = (ushort_t*)w;                       w += (size_t)MROWS * D_MODEL * 2;
    ushort_t* Kbuf   = (ushort_t*)w;                       w += (size_t)MROWS * KVDIM * 2;
    ushort_t* Vt     = (ushort_t*)w;                       w += (size_t)MROWS * KVDIM * 2;
    ushort_t* Obuf   = (ushort_t*)w;                       w += (size_t)MROWS * D_MODEL * 2;
    float*    Pnum   = (float*)w;                          w += (size_t)NSPLIT * NTASK * 64 * 4;
    float*    Pl     = (float*)w;

    // --- prep: casts & weight transposes (all f16)
    cast_kernel<<<(MROWS * D_MODEL / 4 + 255) / 256, 256, 0, stream>>>(
        x, xb, MROWS * D_MODEL / 4);
    transpose_cast<<<dim3(D_MODEL / 32, D_MODEL / 32), 256, 0, stream>>>(
        Wq, WqkvT, D_MODEL, D_MODEL);
    transpose_cast<<<dim3(KVDIM / 32, D_MODEL / 32), 256, 0, stream>>>(
        Wk, WqkvT + (size_t)1024 * D_MODEL, D_MODEL, KVDIM);
    transpose_cast<<<dim3(KVDIM / 32, D_MODEL / 32), 256, 0, stream>>>(
        Wv, WqkvT + (size_t)1280 * D_MODEL, D_MODEL, KVDIM);
    transpose_cast<<<dim3(D_MODEL / 32, D_MODEL / 32), 256, 0, stream>>>(
        Wo, WoT, D_MODEL, D_MODEL);

    // --- fused QKV projection
    gemm_bt<<<dim3(QKVN / 128, MROWS / 128), 256, 0, stream>>>(
        xb, WqkvT, QKVf, MROWS, QKVN, D_MODEL);

    // --- rope + relayout (Q,K), V transpose
    rope_kernel<<<(NQW + NKW) / 256, 256, 0, stream>>>(QKVf, cosp, sinp, Qbuf, Kbuf);
    vtrans_kernel<<<dim3(NN / 32, KVDIM / 32, BB), 256, 0, stream>>>(QKVf, Vt);

    // --- attention (S^T f16, mt=4, split-K x4) + combine
    attn_mfma<<<dim3(NN / 256, NHEADS, BB * NSPLIT), 256, 0, stream>>>(
        Qbuf, Kbuf, Vt, Pnum, Pl);
    attn_combine<<<(NTASK * 16) / 256, 256, 0, stream>>>(Pnum, Pl, Obuf);

    // --- output projection
    gemm_bt<<<dim3(D_MODEL / 128, MROWS / 128), 256, 0, stream>>>(
        Obuf, WoT, out, MROWS, D_MODEL, D_MODEL);
}

// Round 10
// 234.753 us; speedup vs baseline: 1.1176x; 1.1176x over previous
//
#include <hip/hip_runtime.h>
#include <math.h>

#define D_MODEL 1024
#define NHEADS  16
#define NKV     4
#define HDIM    64
#define KVDIM   256
#define BB      2
#define NN      2048
#define MROWS   (BB*NN)        // 4096
#define QKVN    1536           // 1024 + 256 + 256
#define NTASK   (MROWS*NHEADS) // 65536
#define NSPLIT  4

typedef unsigned short ushort_t;
typedef unsigned int uint_t;
typedef float    f32x4 __attribute__((ext_vector_type(4)));
typedef _Float16 h16x8 __attribute__((ext_vector_type(8)));
typedef __fp16   fp16x2 __attribute__((ext_vector_type(2)));

#define MFMAH(A,B,C) __builtin_amdgcn_mfma_f32_16x16x32_f16((A),(B),(C),0,0,0)

// async global->LDS, 16B per lane; LDS dest = wave-uniform base + lane*16
#define GLDS(gp, lp) __builtin_amdgcn_global_load_lds( \
    (const __attribute__((address_space(1))) void*)(gp), \
    (__attribute__((address_space(3))) void*)(lp), 16, 0, 0)

// fp32 -> f16 scalar
__device__ __forceinline__ ushort_t f2h(float f) {
    _Float16 h = (_Float16)f;
    return *(ushort_t*)&h;
}
// two fp32 -> packed f16x2, single v_cvt_pkrtz_f16_f32
__device__ __forceinline__ uint_t pk2h(float a, float b) {
    fp16x2 v = __builtin_amdgcn_cvt_pkrtz(a, b);
    return *(uint_t*)&v;
}

// ---------------------------------------------------------------------------
// castx: fp32 -> f16, 4 elements/thread
// ---------------------------------------------------------------------------
__global__ __launch_bounds__(256)
void cast_kernel(const float* __restrict__ src, ushort_t* __restrict__ dst, int n4)
{
    int i = blockIdx.x * 256 + threadIdx.x;
    if (i >= n4) return;
    float4 v = ((const float4*)src)[i];
    uint2 o;
    o.x = pk2h(v.x, v.y);
    o.y = pk2h(v.z, v.w);
    ((uint2*)dst)[i] = o;
}

// ---------------------------------------------------------------------------
// transpose + cast: src fp32 [K][N] -> dst f16 [N][K]
// ---------------------------------------------------------------------------
__global__ __launch_bounds__(256)
void transpose_cast(const float* __restrict__ src, ushort_t* __restrict__ dst,
                    int K, int N)
{
    __shared__ float T[32][33];
    const int tx = threadIdx.x & 31, ty = threadIdx.x >> 5;
    const int n0 = blockIdx.x * 32, k0 = blockIdx.y * 32;
#pragma unroll
    for (int i = 0; i < 4; i++)
        T[ty + i * 8][tx] = src[(size_t)(k0 + ty + i * 8) * N + n0 + tx];
    __syncthreads();
#pragma unroll
    for (int i = 0; i < 4; i++)
        dst[(size_t)(n0 + ty + i * 8) * K + k0 + tx] = f2h(T[tx][ty + i * 8]);
}

// ---------------------------------------------------------------------------
// V transpose: QKVf cols [1280,1536) per batch -> Vt f16 [(b*256+d)][2048]
// ---------------------------------------------------------------------------
__global__ __launch_bounds__(256)
void vtrans_kernel(const float* __restrict__ QKVf, ushort_t* __restrict__ Vt)
{
    __shared__ float T[32][33];
    const int tx = threadIdx.x & 31, ty = threadIdx.x >> 5;
    const int n0 = blockIdx.x * 32, d0 = blockIdx.y * 32, b = blockIdx.z;
#pragma unroll
    for (int i = 0; i < 4; i++)
        T[ty + i * 8][tx] =
            QKVf[(size_t)(b * NN + n0 + ty + i * 8) * QKVN + 1280 + d0 + tx];
    __syncthreads();
#pragma unroll
    for (int i = 0; i < 4; i++)
        Vt[(size_t)(b * 256 + d0 + ty + i * 8) * NN + n0 + tx] = f2h(T[tx][ty + i * 8]);
}

// ---------------------------------------------------------------------------
// RoPE + cast(f16) + relayout for Q and K (reads fp32 QKVf).
// Q gets 0.125*log2(e) folded in (softmax runs base-2).
// ---------------------------------------------------------------------------
#define NQW (MROWS*NHEADS*32)   // 2,097,152
#define NKW (MROWS*NKV*32)      //   524,288
__global__ __launch_bounds__(256)
void rope_kernel(const float* __restrict__ QKVf, const float* __restrict__ Cos,
                 const float* __restrict__ Sin, ushort_t* __restrict__ Qb,
                 ushort_t* __restrict__ Kb)
{
    const float SC = 0.125f * 1.44269504f;
    int idx = blockIdx.x * 256 + threadIdx.x;
    if (idx < NQW) {
        const int row = idx >> 9, rem = idx & 511;
        const int h = rem >> 5, j = rem & 31;
        const int b = row >> 11, n = row & (NN - 1);
        const float* s_ = QKVf + (size_t)row * QKVN + h * 64;
        const float e = s_[2 * j], o = s_[2 * j + 1];
        const float c = Cos[n * 32 + j], s = Sin[n * 32 + j];
        ushort_t* dst = Qb + ((size_t)(b * 16 + h) * NN + n) * 64;
        dst[j]      = f2h((e * c - o * s) * SC);
        dst[j + 32] = f2h((e * s + o * c) * SC);
    } else {
        const int i2 = idx - NQW;
        const int row = i2 >> 7, rem = i2 & 127;
        const int h = rem >> 5, j = rem & 31;
        const int b = row >> 11, n = row & (NN - 1);
        const float* s_ = QKVf + (size_t)row * QKVN + 1024 + h * 64;
        const float e = s_[2 * j], o = s_[2 * j + 1];
        const float c = Cos[n * 32 + j], s = Sin[n * 32 + j];
        ushort_t* dst = Kb + ((size_t)(b * 4 + h) * NN + n) * 64;
        dst[j]      = f2h(e * c - o * s);
        dst[j + 32] = f2h(e * s + o * c);
    }
}

// ---------------------------------------------------------------------------
// f16 MFMA GEMM, B^T form, GLDS staging + XOR column-block swizzle.
// LDS tile [128][32] unpadded (GLDS needs exact lane-order dest), but the
// 16B column block stored at (row, b) holds GLOBAL block b ^ ((row>>1)&3).
// Frag reads then use col (quad ^ ((l16>>1)&3))*8 -> 16B-slot v*4+(q^w):
// all 8 slots hit exactly 2x over 16 lanes = conflict-free (2-way is free).
// ---------------------------------------------------------------------------
__global__ __launch_bounds__(256)
void gemm_bt(const ushort_t* __restrict__ A, const ushort_t* __restrict__ Bt,
             float* __restrict__ C, int M, int N, int K)
{
    __shared__ ushort_t As[128 * 32];
    __shared__ ushort_t Bs[128 * 32];

    const int tid  = threadIdx.x;
    const int wave = tid >> 6, lane = tid & 63;
    const int quad = lane >> 4, l16 = lane & 15;
    const int rowBase = blockIdx.y * 128, colBase = blockIdx.x * 128;
    const int wm = (wave >> 1) * 64, wn = (wave & 1) * 64;

    f32x4 acc[4][4];
    const f32x4 zz = {0.f, 0.f, 0.f, 0.f};
#pragma unroll
    for (int i = 0; i < 4; i++)
#pragma unroll
        for (int j = 0; j < 4; j++) acc[i][j] = zz;

    // staging: lane l -> row seg + l>>2; stored block b = l&3 receives
    // global block g = b ^ ((l>>3)&3)   [(row>>1)&3 within the 16-row seg]
    const int sr = wave * 32 + (lane >> 2);
    const int sc = ((lane & 3) ^ ((lane >> 3) & 3)) * 8;
    const ushort_t* Ag0 = A  + (size_t)(rowBase + sr) * K + sc;
    const ushort_t* Ag1 = A  + (size_t)(rowBase + sr + 16) * K + sc;
    const ushort_t* Bg0 = Bt + (size_t)(colBase + sr) * K + sc;
    const ushort_t* Bg1 = Bt + (size_t)(colBase + sr + 16) * K + sc;
    ushort_t* Al0 = &As[(wave * 2 + 0) * 512];
    ushort_t* Al1 = &As[(wave * 2 + 1) * 512];
    ushort_t* Bl0 = &Bs[(wave * 2 + 0) * 512];
    ushort_t* Bl1 = &Bs[(wave * 2 + 1) * 512];

    // frag-read swizzled column (row multiple-of-16 offsets drop out)
    const int fcol = (quad ^ ((l16 >> 1) & 3)) * 8;

    for (int k0 = 0; k0 < K; k0 += 32) {
        __syncthreads();                 // prev-iter frag reads done
        GLDS(Ag0 + k0, Al0);
        GLDS(Ag1 + k0, Al1);
        GLDS(Bg0 + k0, Bl0);
        GLDS(Bg1 + k0, Bl1);
        __syncthreads();                 // drains vmcnt -> LDS valid

        h16x8 af[4], bf[4];
#pragma unroll
        for (int mt = 0; mt < 4; mt++)
            af[mt] = *(const h16x8*)&As[(wm + mt * 16 + l16) * 32 + fcol];
#pragma unroll
        for (int nt = 0; nt < 4; nt++)
            bf[nt] = *(const h16x8*)&Bs[(wn + nt * 16 + l16) * 32 + fcol];
#pragma unroll
        for (int mt = 0; mt < 4; mt++)
#pragma unroll
            for (int nt = 0; nt < 4; nt++)
                acc[mt][nt] = MFMAH(af[mt], bf[nt], acc[mt][nt]);
    }

#pragma unroll
    for (int mt = 0; mt < 4; mt++)
#pragma unroll
        for (int nt = 0; nt < 4; nt++) {
            const int row = rowBase + wm + mt * 16 + quad * 4;
            const int col = colBase + wn + nt * 16 + l16;
#pragma unroll
            for (int r = 0; r < 4; r++)
                C[(size_t)(row + r) * N + col] = acc[mt][nt][r];
        }
}

// ---------------------------------------------------------------------------
// MFMA flash attention v6: S^T form, f16, mt=4 amortization, but P staged
// through a SINGLE per-wave 16-row LDS slot reused serially across mt —
// packed P lives in registers (pkreg[4][4] uint2) between phases.
// LDS: Ks 9K + Vs 9K + Ps 4x2.25K = 27.6 KB (was 54 KB in v5).
// Split-K x4, no-max softmax (order-invariant -> rotated key start).
// ---------------------------------------------------------------------------
__global__ __launch_bounds__(256)
void attn_mfma(const ushort_t* __restrict__ Qb, const ushort_t* __restrict__ Kb,
               const ushort_t* __restrict__ Vt, float* __restrict__ Pnum,
               float* __restrict__ Pl)
{
    const int qt = blockIdx.x, h = blockIdx.y;
    const int b = blockIdx.z >> 2, chunk = blockIdx.z & 3;
    const int kvh = h >> 2;
    const int tid = threadIdx.x;
    const int wave = tid >> 6, lane = tid & 63;
    const int quad = lane >> 4, l16 = lane & 15;

    __shared__ ushort_t Ks[64][72];      // [key][dim]
    __shared__ ushort_t Vs[64][72];      // [dim][key]
    __shared__ ushort_t Ps[4][16 * 72];  // per-wave P^T slot [qrow][key], reused per mt
    ushort_t* ps = &Ps[wave][0];

    // ---- Q B-frags: 64 rows per wave (4 m-tiles), resident in registers
    const int row0 = qt * 256 + wave * 64;
    h16x8 qf[4][2];
#pragma unroll
    for (int mt = 0; mt < 4; mt++) {
        const ushort_t* qp =
            Qb + ((size_t)(b * 16 + h) * NN + row0 + mt * 16 + l16) * 64 + quad * 8;
        qf[mt][0] = *(const h16x8*)qp;
        qf[mt][1] = *(const h16x8*)(qp + 32);
    }

    const ushort_t* kbase = Kb + (size_t)(b * 4 + kvh) * NN * 64;
    const ushort_t* vbase = Vt + (size_t)(b * 256 + kvh * 64) * NN;
    const int key_lo = chunk * (NN / NSPLIT);          // 512-key chunk
    const int rot = (qt + ((h & 3) << 1)) & 7;

    const int srow = tid >> 2, sseg = (tid & 3) * 8;

    const f32x4 zz = {0.f, 0.f, 0.f, 0.f};
    f32x4 o[4][4];
#pragma unroll
    for (int mt = 0; mt < 4; mt++)
#pragma unroll
        for (int dt = 0; dt < 4; dt++) o[mt][dt] = zz;
    float lacc[4] = {0.f, 0.f, 0.f, 0.f};

    // prefetch tile 0
    int key0 = key_lo + rot * 64;
    const ushort_t* kp0 = kbase + (size_t)(key0 + srow) * 64 + sseg;
    const ushort_t* vp0 = vbase + (size_t)srow * NN + key0 + sseg;
    uint4 kreg0 = *(const uint4*)kp0;
    uint4 kreg1 = *(const uint4*)(kp0 + 32);
    uint4 vreg0 = *(const uint4*)vp0;
    uint4 vreg1 = *(const uint4*)(vp0 + 32);

    for (int t = 0; t < 8; t++) {
        __syncthreads();
        *(uint4*)&Ks[srow][sseg]      = kreg0;
        *(uint4*)&Ks[srow][sseg + 32] = kreg1;
        *(uint4*)&Vs[srow][sseg]      = vreg0;
        *(uint4*)&Vs[srow][sseg + 32] = vreg1;
        __syncthreads();

        if (t < 7) {
            const int kn = key_lo + ((rot + t + 1) & 7) * 64;
            const ushort_t* kpn = kbase + (size_t)(kn + srow) * 64 + sseg;
            const ushort_t* vpn = vbase + (size_t)srow * NN + kn + sseg;
            kreg0 = *(const uint4*)kpn;
            kreg1 = *(const uint4*)(kpn + 32);
            vreg0 = *(const uint4*)vpn;
            vreg1 = *(const uint4*)(vpn + 32);
        }

        // ---- Phase 1: S^T = K Q^T for all kt x mt; exp2 + pack to registers
        uint2 pkreg[4][4];   // [kt][mt]
#pragma unroll
        for (int kt = 0; kt < 4; kt++) {
            h16x8 kf0 = *(const h16x8*)&Ks[kt * 16 + l16][quad * 8];
            h16x8 kf1 = *(const h16x8*)&Ks[kt * 16 + l16][32 + quad * 8];
#pragma unroll
            for (int mt = 0; mt < 4; mt++) {
                f32x4 st = MFMAH(kf0, qf[mt][0], zz);
                st = MFMAH(kf1, qf[mt][1], st);
                const float p0 = exp2f(st[0]);
                const float p1 = exp2f(st[1]);
                const float p2 = exp2f(st[2]);
                const float p3 = exp2f(st[3]);
                lacc[mt] += (p0 + p1) + (p2 + p3);
                pkreg[kt][mt].x = pk2h(p0, p1);
                pkreg[kt][mt].y = pk2h(p2, p3);
            }
        }

        // ---- Phase 2: per mt: write P^T slot, read A-frags, PV MFMAs
        h16x8 vf[4][2];
#pragma unroll
        for (int dt = 0; dt < 4; dt++) {
            vf[dt][0] = *(const h16x8*)&Vs[dt * 16 + l16][quad * 8];
            vf[dt][1] = *(const h16x8*)&Vs[dt * 16 + l16][32 + quad * 8];
        }
#pragma unroll
        for (int mt = 0; mt < 4; mt++) {
#pragma unroll
            for (int kt = 0; kt < 4; kt++)
                *(uint2*)&ps[l16 * 72 + kt * 16 + quad * 4] = pkreg[kt][mt];
            h16x8 pa0 = *(const h16x8*)&ps[l16 * 72 + quad * 8];
            h16x8 pa1 = *(const h16x8*)&ps[l16 * 72 + 32 + quad * 8];
#pragma unroll
            for (int dt = 0; dt < 4; dt++) {
                o[mt][dt] = MFMAH(vf[dt][0], pa0, o[mt][dt]);
                o[mt][dt] = MFMAH(vf[dt][1], pa1, o[mt][dt]);
            }
        }
    }

    // ---- reduce l across the 4 quads — once per kernel
#pragma unroll
    for (int mt = 0; mt < 4; mt++) {
        lacc[mt] += __shfl_xor(lacc[mt], 16, 64);
        lacc[mt] += __shfl_xor(lacc[mt], 32, 64);
    }

    // ---- write unnormalized partials (contiguous float4 stores)
    const size_t task0 = (size_t)(b * 16 + h) * NN + row0;
    float* np = Pnum + ((size_t)chunk * NTASK + task0) * 64;
#pragma unroll
    for (int mt = 0; mt < 4; mt++) {
#pragma unroll
        for (int dt = 0; dt < 4; dt++) {
            f32x4 v = o[mt][dt];
            *(float4*)&np[(size_t)(mt * 16 + l16) * 64 + dt * 16 + quad * 4] =
                make_float4(v[0], v[1], v[2], v[3]);
        }
        if (quad == 0)
            Pl[(size_t)chunk * NTASK + task0 + mt * 16 + l16] = lacc[mt];
    }
}

// ---------------------------------------------------------------------------
// Combine 4 split partials: O = sum(num_s)/sum(l_s), write f16 Ob.
// ---------------------------------------------------------------------------
__global__ __launch_bounds__(256)
void attn_combine(const float* __restrict__ Pnum, const float* __restrict__ Pl,
                  ushort_t* __restrict__ Ob)
{
    const int gid  = blockIdx.x * 256 + threadIdx.x;
    const int task = gid >> 4;
    const int d    = (gid & 15) * 4;
    float4 acc = make_float4(0.f, 0.f, 0.f, 0.f);
    float l = 0.f;
#pragma unroll
    for (int s = 0; s < NSPLIT; s++) {
        const float4 v = *(const float4*)&Pnum[((size_t)s * NTASK + task) * 64 + d];
        acc.x += v.x; acc.y += v.y; acc.z += v.z; acc.w += v.w;
        l += Pl[(size_t)s * NTASK + task];
    }
    const float inv = 1.0f / l;
    const int n = task & (NN - 1), bh = task >> 11;
    const int h = bh & (NHEADS - 1), b = bh >> 4;
    ushort_t* op = Ob + (size_t)(b * NN + n) * D_MODEL + h * 64 + d;
    uint2 o2;
    o2.x = pk2h(acc.x * inv, acc.y * inv);
    o2.y = pk2h(acc.z * inv, acc.w * inv);
    *(uint2*)op = o2;
}

// ---------------------------------------------------------------------------
extern "C" void kernel_launch(void* const* d_in, const int* in_sizes, int n_in,
                              void* d_out, int out_size, void* d_ws, size_t ws_size,
                              hipStream_t stream)
{
    const float* x    = (const float*)d_in[0];
    const float* cosp = (const float*)d_in[1];
    const float* sinp = (const float*)d_in[2];
    const float* Wq   = (const float*)d_in[3];
    const float* Wk   = (const float*)d_in[4];
    const float* Wv   = (const float*)d_in[5];
    const float* Wo   = (const float*)d_in[6];
    float* out = (float*)d_out;

    char* w = (char*)d_ws;
    ushort_t* xb     = (ushort_t*)w;                       w += (size_t)MROWS * D_MODEL * 2;
    ushort_t* WqkvT  = (ushort_t*)w;                       w += (size_t)QKVN * D_MODEL * 2;
    ushort_t* WoT    = (ushort_t*)w;                       w += (size_t)D_MODEL * D_MODEL * 2;
    float*    QKVf   = (float*)w;                          w += (size_t)MROWS * QKVN * 4;
    ushort_t* Qbuf   = (ushort_t*)w;                       w += (size_t)MROWS * D_MODEL * 2;
    ushort_t* Kbuf   = (ushort_t*)w;                       w += (size_t)MROWS * KVDIM * 2;
    ushort_t* Vt     = (ushort_t*)w;                       w += (size_t)MROWS * KVDIM * 2;
    ushort_t* Obuf   = (ushort_t*)w;                       w += (size_t)MROWS * D_MODEL * 2;
    float*    Pnum   = (float*)w;                          w += (size_t)NSPLIT * NTASK * 64 * 4;
    float*    Pl     = (float*)w;

    // --- prep: casts & weight transposes (all f16)
    cast_kernel<<<(MROWS * D_MODEL / 4 + 255) / 256, 256, 0, stream>>>(
        x, xb, MROWS * D_MODEL / 4);
    transpose_cast<<<dim3(D_MODEL / 32, D_MODEL / 32), 256, 0, stream>>>(
        Wq, WqkvT, D_MODEL, D_MODEL);
    transpose_cast<<<dim3(KVDIM / 32, D_MODEL / 32), 256, 0, stream>>>(
        Wk, WqkvT + (size_t)1024 * D_MODEL, D_MODEL, KVDIM);
    transpose_cast<<<dim3(KVDIM / 32, D_MODEL / 32), 256, 0, stream>>>(
        Wv, WqkvT + (size_t)1280 * D_MODEL, D_MODEL, KVDIM);
    transpose_cast<<<dim3(D_MODEL / 32, D_MODEL / 32), 256, 0, stream>>>(
        Wo, WoT, D_MODEL, D_MODEL);

    // --- fused QKV projection
    gemm_bt<<<dim3(QKVN / 128, MROWS / 128), 256, 0, stream>>>(
        xb, WqkvT, QKVf, MROWS, QKVN, D_MODEL);

    // --- rope + relayout (Q,K), V transpose
    rope_kernel<<<(NQW + NKW) / 256, 256, 0, stream>>>(QKVf, cosp, sinp, Qbuf, Kbuf);
    vtrans_kernel<<<dim3(NN / 32, KVDIM / 32, BB), 256, 0, stream>>>(QKVf, Vt);

    // --- attention (S^T f16, mt=4, slot-reuse P, split-K x4) + combine
    attn_mfma<<<dim3(NN / 256, NHEADS, BB * NSPLIT), 256, 0, stream>>>(
        Qbuf, Kbuf, Vt, Pnum, Pl);
    attn_combine<<<(NTASK * 16) / 256, 256, 0, stream>>>(Pnum, Pl, Obuf);

    // --- output projection
    gemm_bt<<<dim3(D_MODEL / 128, MROWS / 128), 256, 0, stream>>>(
        Obuf, WoT, out, MROWS, D_MODEL, D_MODEL);
}

// Round 11
// 220.910 us; speedup vs baseline: 1.1877x; 1.0627x over previous
//
#include <hip/hip_runtime.h>
#include <math.h>

#define D_MODEL 1024
#define NHEADS  16
#define NKV     4
#define HDIM    64
#define KVDIM   256
#define BB      2
#define NN      2048
#define MROWS   (BB*NN)        // 4096
#define QKVN    1536           // 1024 + 256 + 256
#define NTASK   (MROWS*NHEADS) // 65536
#define NSPLIT  4

typedef unsigned short ushort_t;
typedef unsigned int uint_t;
typedef float    f32x4 __attribute__((ext_vector_type(4)));
typedef _Float16 h16x8 __attribute__((ext_vector_type(8)));
typedef __fp16   fp16x2 __attribute__((ext_vector_type(2)));

#define MFMAH(A,B,C) __builtin_amdgcn_mfma_f32_16x16x32_f16((A),(B),(C),0,0,0)

// async global->LDS, 16B per lane; LDS dest = wave-uniform base + lane*16
#define GLDS(gp, lp) __builtin_amdgcn_global_load_lds( \
    (const __attribute__((address_space(1))) void*)(gp), \
    (__attribute__((address_space(3))) void*)(lp), 16, 0, 0)

__device__ __forceinline__ ushort_t f2h(float f) {
    _Float16 h = (_Float16)f;
    return *(ushort_t*)&h;
}
__device__ __forceinline__ float h2f(ushort_t u) {
    return (float)(*(const _Float16*)&u);
}
// two fp32 -> packed f16x2, single v_cvt_pkrtz_f16_f32
__device__ __forceinline__ uint_t pk2h(float a, float b) {
    fp16x2 v = __builtin_amdgcn_cvt_pkrtz(a, b);
    return *(uint_t*)&v;
}

// ---------------------------------------------------------------------------
// castx: fp32 -> f16, 4 elements/thread
// ---------------------------------------------------------------------------
__global__ __launch_bounds__(256)
void cast_kernel(const float* __restrict__ src, ushort_t* __restrict__ dst, int n4)
{
    int i = blockIdx.x * 256 + threadIdx.x;
    if (i >= n4) return;
    float4 v = ((const float4*)src)[i];
    uint2 o;
    o.x = pk2h(v.x, v.y);
    o.y = pk2h(v.z, v.w);
    ((uint2*)dst)[i] = o;
}

// ---------------------------------------------------------------------------
// transpose + cast: src fp32 [K][N] -> dst f16 [N][K]
// ---------------------------------------------------------------------------
__global__ __launch_bounds__(256)
void transpose_cast(const float* __restrict__ src, ushort_t* __restrict__ dst,
                    int K, int N)
{
    __shared__ float T[32][33];
    const int tx = threadIdx.x & 31, ty = threadIdx.x >> 5;
    const int n0 = blockIdx.x * 32, k0 = blockIdx.y * 32;
#pragma unroll
    for (int i = 0; i < 4; i++)
        T[ty + i * 8][tx] = src[(size_t)(k0 + ty + i * 8) * N + n0 + tx];
    __syncthreads();
#pragma unroll
    for (int i = 0; i < 4; i++)
        dst[(size_t)(n0 + ty + i * 8) * K + k0 + tx] = f2h(T[tx][ty + i * 8]);
}

// ---------------------------------------------------------------------------
// V transpose: QKVh (f16) cols [1280,1536) per batch -> Vt f16 [(b*256+d)][2048]
// ---------------------------------------------------------------------------
__global__ __launch_bounds__(256)
void vtrans_kernel(const ushort_t* __restrict__ QKVh, ushort_t* __restrict__ Vt)
{
    __shared__ ushort_t T[32][34];   // pad 2 ushorts: col stride 17 dwords, coprime 32
    const int tx = threadIdx.x & 31, ty = threadIdx.x >> 5;
    const int n0 = blockIdx.x * 32, d0 = blockIdx.y * 32, b = blockIdx.z;
#pragma unroll
    for (int i = 0; i < 4; i++)
        T[ty + i * 8][tx] =
            QKVh[(size_t)(b * NN + n0 + ty + i * 8) * QKVN + 1280 + d0 + tx];
    __syncthreads();
#pragma unroll
    for (int i = 0; i < 4; i++)
        Vt[(size_t)(b * 256 + d0 + ty + i * 8) * NN + n0 + tx] = T[tx][ty + i * 8];
}

// ---------------------------------------------------------------------------
// RoPE (f16 in/out) + relayout for Q and K.
// Q gets 0.125*log2(e) folded in (softmax runs base-2).
// ---------------------------------------------------------------------------
#define NQW (MROWS*NHEADS*32)   // 2,097,152
#define NKW (MROWS*NKV*32)      //   524,288
__global__ __launch_bounds__(256)
void rope_kernel(const ushort_t* __restrict__ QKVh, const float* __restrict__ Cos,
                 const float* __restrict__ Sin, ushort_t* __restrict__ Qb,
                 ushort_t* __restrict__ Kb)
{
    const float SC = 0.125f * 1.44269504f;
    int idx = blockIdx.x * 256 + threadIdx.x;
    if (idx < NQW) {
        const int row = idx >> 9, rem = idx & 511;
        const int h = rem >> 5, j = rem & 31;
        const int b = row >> 11, n = row & (NN - 1);
        const uint_t pr = *(const uint_t*)&QKVh[(size_t)row * QKVN + h * 64 + 2 * j];
        const float e = h2f((ushort_t)pr), o = h2f((ushort_t)(pr >> 16));
        const float c = Cos[n * 32 + j], s = Sin[n * 32 + j];
        ushort_t* dst = Qb + ((size_t)(b * 16 + h) * NN + n) * 64;
        dst[j]      = f2h((e * c - o * s) * SC);
        dst[j + 32] = f2h((e * s + o * c) * SC);
    } else {
        const int i2 = idx - NQW;
        const int row = i2 >> 7, rem = i2 & 127;
        const int h = rem >> 5, j = rem & 31;
        const int b = row >> 11, n = row & (NN - 1);
        const uint_t pr = *(const uint_t*)&QKVh[(size_t)row * QKVN + 1024 + h * 64 + 2 * j];
        const float e = h2f((ushort_t)pr), o = h2f((ushort_t)(pr >> 16));
        const float c = Cos[n * 32 + j], s = Sin[n * 32 + j];
        ushort_t* dst = Kb + ((size_t)(b * 4 + h) * NN + n) * 64;
        dst[j]      = f2h(e * c - o * s);
        dst[j + 32] = f2h(e * s + o * c);
    }
}

// ---------------------------------------------------------------------------
// f16 MFMA GEMM, B^T form, GLDS + XOR swizzle + DOUBLE-BUFFERED LDS.
// Prefetch for tile t+1 is issued right after the barrier, before computing
// tile t -> the ~200cyc L2 latency hides behind frag reads + 16 MFMAs.
// One barrier per iteration. halfout: 1 -> C is f16 (ushort), else fp32.
// ---------------------------------------------------------------------------
__global__ __launch_bounds__(256)
void gemm_bt(const ushort_t* __restrict__ A, const ushort_t* __restrict__ Bt,
             void* __restrict__ C, int M, int N, int K, int halfout)
{
    __shared__ ushort_t As[2][128 * 32];
    __shared__ ushort_t Bs[2][128 * 32];

    const int tid  = threadIdx.x;
    const int wave = tid >> 6, lane = tid & 63;
    const int quad = lane >> 4, l16 = lane & 15;
    const int rowBase = blockIdx.y * 128, colBase = blockIdx.x * 128;
    const int wm = (wave >> 1) * 64, wn = (wave & 1) * 64;

    f32x4 acc[4][4];
    const f32x4 zz = {0.f, 0.f, 0.f, 0.f};
#pragma unroll
    for (int i = 0; i < 4; i++)
#pragma unroll
        for (int j = 0; j < 4; j++) acc[i][j] = zz;

    // staging: lane l -> row seg + l>>2; stored block b = l&3 holds
    // global block (l&3) ^ ((l>>3)&3)  [xor-swizzle kills 8-way conflicts]
    const int sr = wave * 32 + (lane >> 2);
    const int sc = ((lane & 3) ^ ((lane >> 3) & 3)) * 8;
    const ushort_t* Ag0 = A  + (size_t)(rowBase + sr) * K + sc;
    const ushort_t* Ag1 = A  + (size_t)(rowBase + sr + 16) * K + sc;
    const ushort_t* Bg0 = Bt + (size_t)(colBase + sr) * K + sc;
    const ushort_t* Bg1 = Bt + (size_t)(colBase + sr + 16) * K + sc;
    const int seg0 = (wave * 2 + 0) * 512, seg1 = (wave * 2 + 1) * 512;

    // frag-read swizzled column
    const int fcol = (quad ^ ((l16 >> 1) & 3)) * 8;

    // prologue: stage tile 0 into buffer 0
    GLDS(Ag0, &As[0][seg0]);
    GLDS(Ag1, &As[0][seg1]);
    GLDS(Bg0, &Bs[0][seg0]);
    GLDS(Bg1, &Bs[0][seg1]);

    for (int k0 = 0; k0 < K; k0 += 32) {
        const int cur = (k0 >> 5) & 1, nxt = cur ^ 1;
        __syncthreads();   // drains staging for buf[cur]; frees buf[nxt]
        if (k0 + 32 < K) {
            GLDS(Ag0 + k0 + 32, &As[nxt][seg0]);
            GLDS(Ag1 + k0 + 32, &As[nxt][seg1]);
            GLDS(Bg0 + k0 + 32, &Bs[nxt][seg0]);
            GLDS(Bg1 + k0 + 32, &Bs[nxt][seg1]);
        }

        h16x8 af[4], bf[4];
#pragma unroll
        for (int mt = 0; mt < 4; mt++)
            af[mt] = *(const h16x8*)&As[cur][(wm + mt * 16 + l16) * 32 + fcol];
#pragma unroll
        for (int nt = 0; nt < 4; nt++)
            bf[nt] = *(const h16x8*)&Bs[cur][(wn + nt * 16 + l16) * 32 + fcol];
#pragma unroll
        for (int mt = 0; mt < 4; mt++)
#pragma unroll
            for (int nt = 0; nt < 4; nt++)
                acc[mt][nt] = MFMAH(af[mt], bf[nt], acc[mt][nt]);
    }

    if (halfout) {
        ushort_t* Ch = (ushort_t*)C;
#pragma unroll
        for (int mt = 0; mt < 4; mt++)
#pragma unroll
            for (int nt = 0; nt < 4; nt++) {
                const int row = rowBase + wm + mt * 16 + quad * 4;
                const int col = colBase + wn + nt * 16 + l16;
#pragma unroll
                for (int r = 0; r < 4; r++)
                    Ch[(size_t)(row + r) * N + col] = f2h(acc[mt][nt][r]);
            }
    } else {
        float* Cf = (float*)C;
#pragma unroll
        for (int mt = 0; mt < 4; mt++)
#pragma unroll
            for (int nt = 0; nt < 4; nt++) {
                const int row = rowBase + wm + mt * 16 + quad * 4;
                const int col = colBase + wn + nt * 16 + l16;
#pragma unroll
                for (int r = 0; r < 4; r++)
                    Cf[(size_t)(row + r) * N + col] = acc[mt][nt][r];
            }
    }
}

// ---------------------------------------------------------------------------
// MFMA flash attention v7: S^T form, f16, mt=4, slot-reuse P (v6 core),
// epilogue now writes NORMALIZED per-chunk f16 partials (o/l, |.|<~4) ->
// halves the partial-buffer traffic. Split-K x4, no-max softmax.
// ---------------------------------------------------------------------------
__global__ __launch_bounds__(256)
void attn_mfma(const ushort_t* __restrict__ Qb, const ushort_t* __restrict__ Kb,
               const ushort_t* __restrict__ Vt, ushort_t* __restrict__ Pnum,
               float* __restrict__ Pl)
{
    const int qt = blockIdx.x, h = blockIdx.y;
    const int b = blockIdx.z >> 2, chunk = blockIdx.z & 3;
    const int kvh = h >> 2;
    const int tid = threadIdx.x;
    const int wave = tid >> 6, lane = tid & 63;
    const int quad = lane >> 4, l16 = lane & 15;

    __shared__ ushort_t Ks[64][72];      // [key][dim]
    __shared__ ushort_t Vs[64][72];      // [dim][key]
    __shared__ ushort_t Ps[4][16 * 72];  // per-wave P^T slot, reused per mt
    ushort_t* ps = &Ps[wave][0];

    const int row0 = qt * 256 + wave * 64;
    h16x8 qf[4][2];
#pragma unroll
    for (int mt = 0; mt < 4; mt++) {
        const ushort_t* qp =
            Qb + ((size_t)(b * 16 + h) * NN + row0 + mt * 16 + l16) * 64 + quad * 8;
        qf[mt][0] = *(const h16x8*)qp;
        qf[mt][1] = *(const h16x8*)(qp + 32);
    }

    const ushort_t* kbase = Kb + (size_t)(b * 4 + kvh) * NN * 64;
    const ushort_t* vbase = Vt + (size_t)(b * 256 + kvh * 64) * NN;
    const int key_lo = chunk * (NN / NSPLIT);
    const int rot = (qt + ((h & 3) << 1)) & 7;

    const int srow = tid >> 2, sseg = (tid & 3) * 8;

    const f32x4 zz = {0.f, 0.f, 0.f, 0.f};
    f32x4 o[4][4];
#pragma unroll
    for (int mt = 0; mt < 4; mt++)
#pragma unroll
        for (int dt = 0; dt < 4; dt++) o[mt][dt] = zz;
    float lacc[4] = {0.f, 0.f, 0.f, 0.f};

    int key0 = key_lo + rot * 64;
    const ushort_t* kp0 = kbase + (size_t)(key0 + srow) * 64 + sseg;
    const ushort_t* vp0 = vbase + (size_t)srow * NN + key0 + sseg;
    uint4 kreg0 = *(const uint4*)kp0;
    uint4 kreg1 = *(const uint4*)(kp0 + 32);
    uint4 vreg0 = *(const uint4*)vp0;
    uint4 vreg1 = *(const uint4*)(vp0 + 32);

    for (int t = 0; t < 8; t++) {
        __syncthreads();
        *(uint4*)&Ks[srow][sseg]      = kreg0;
        *(uint4*)&Ks[srow][sseg + 32] = kreg1;
        *(uint4*)&Vs[srow][sseg]      = vreg0;
        *(uint4*)&Vs[srow][sseg + 32] = vreg1;
        __syncthreads();

        if (t < 7) {
            const int kn = key_lo + ((rot + t + 1) & 7) * 64;
            const ushort_t* kpn = kbase + (size_t)(kn + srow) * 64 + sseg;
            const ushort_t* vpn = vbase + (size_t)srow * NN + kn + sseg;
            kreg0 = *(const uint4*)kpn;
            kreg1 = *(const uint4*)(kpn + 32);
            vreg0 = *(const uint4*)vpn;
            vreg1 = *(const uint4*)(vpn + 32);
        }

        // ---- Phase 1: S^T = K Q^T; exp2 + pack to registers
        uint2 pkreg[4][4];   // [kt][mt]
#pragma unroll
        for (int kt = 0; kt < 4; kt++) {
            h16x8 kf0 = *(const h16x8*)&Ks[kt * 16 + l16][quad * 8];
            h16x8 kf1 = *(const h16x8*)&Ks[kt * 16 + l16][32 + quad * 8];
#pragma unroll
            for (int mt = 0; mt < 4; mt++) {
                f32x4 st = MFMAH(kf0, qf[mt][0], zz);
                st = MFMAH(kf1, qf[mt][1], st);
                const float p0 = exp2f(st[0]);
                const float p1 = exp2f(st[1]);
                const float p2 = exp2f(st[2]);
                const float p3 = exp2f(st[3]);
                lacc[mt] += (p0 + p1) + (p2 + p3);
                pkreg[kt][mt].x = pk2h(p0, p1);
                pkreg[kt][mt].y = pk2h(p2, p3);
            }
        }

        // ---- Phase 2: per mt: write P^T slot, read A-frags, PV MFMAs
        h16x8 vf[4][2];
#pragma unroll
        for (int dt = 0; dt < 4; dt++) {
            vf[dt][0] = *(const h16x8*)&Vs[dt * 16 + l16][quad * 8];
            vf[dt][1] = *(const h16x8*)&Vs[dt * 16 + l16][32 + quad * 8];
        }
#pragma unroll
        for (int mt = 0; mt < 4; mt++) {
#pragma unroll
            for (int kt = 0; kt < 4; kt++)
                *(uint2*)&ps[l16 * 72 + kt * 16 + quad * 4] = pkreg[kt][mt];
            h16x8 pa0 = *(const h16x8*)&ps[l16 * 72 + quad * 8];
            h16x8 pa1 = *(const h16x8*)&ps[l16 * 72 + 32 + quad * 8];
#pragma unroll
            for (int dt = 0; dt < 4; dt++) {
                o[mt][dt] = MFMAH(vf[dt][0], pa0, o[mt][dt]);
                o[mt][dt] = MFMAH(vf[dt][1], pa1, o[mt][dt]);
            }
        }
    }

    // ---- reduce l across the 4 quads — once per kernel
#pragma unroll
    for (int mt = 0; mt < 4; mt++) {
        lacc[mt] += __shfl_xor(lacc[mt], 16, 64);
        lacc[mt] += __shfl_xor(lacc[mt], 32, 64);
    }

    // ---- write normalized f16 partials (uint2 stores) + l
    const size_t task0 = (size_t)(b * 16 + h) * NN + row0;
    ushort_t* np = Pnum + ((size_t)chunk * NTASK + task0) * 64;
#pragma unroll
    for (int mt = 0; mt < 4; mt++) {
        const float inv = 1.0f / lacc[mt];
#pragma unroll
        for (int dt = 0; dt < 4; dt++) {
            f32x4 v = o[mt][dt];
            uint2 pk;
            pk.x = pk2h(v[0] * inv, v[1] * inv);
            pk.y = pk2h(v[2] * inv, v[3] * inv);
            *(uint2*)&np[(size_t)(mt * 16 + l16) * 64 + dt * 16 + quad * 4] = pk;
        }
        if (quad == 0)
            Pl[(size_t)chunk * NTASK + task0 + mt * 16 + l16] = lacc[mt];
    }
}

// ---------------------------------------------------------------------------
// Combine: O = sum(l_s * ohat_s) / sum(l_s), f16 in/out.
// ---------------------------------------------------------------------------
__global__ __launch_bounds__(256)
void attn_combine(const ushort_t* __restrict__ Pnum, const float* __restrict__ Pl,
                  ushort_t* __restrict__ Ob)
{
    const int gid  = blockIdx.x * 256 + threadIdx.x;
    const int task = gid >> 4;
    const int d    = (gid & 15) * 4;
    float a0 = 0.f, a1 = 0.f, a2 = 0.f, a3 = 0.f, lsum = 0.f;
#pragma unroll
    for (int s = 0; s < NSPLIT; s++) {
        const uint2 pk = *(const uint2*)&Pnum[((size_t)s * NTASK + task) * 64 + d];
        const float l = Pl[(size_t)s * NTASK + task];
        const fp16x2 lo = *(const fp16x2*)&pk.x;
        const fp16x2 hi = *(const fp16x2*)&pk.y;
        a0 += l * (float)lo.x; a1 += l * (float)lo.y;
        a2 += l * (float)hi.x; a3 += l * (float)hi.y;
        lsum += l;
    }
    const float inv = 1.0f / lsum;
    const int n = task & (NN - 1), bh = task >> 11;
    const int h = bh & (NHEADS - 1), b = bh >> 4;
    ushort_t* op = Ob + (size_t)(b * NN + n) * D_MODEL + h * 64 + d;
    uint2 o2;
    o2.x = pk2h(a0 * inv, a1 * inv);
    o2.y = pk2h(a2 * inv, a3 * inv);
    *(uint2*)op = o2;
}

// ---------------------------------------------------------------------------
extern "C" void kernel_launch(void* const* d_in, const int* in_sizes, int n_in,
                              void* d_out, int out_size, void* d_ws, size_t ws_size,
                              hipStream_t stream)
{
    const float* x    = (const float*)d_in[0];
    const float* cosp = (const float*)d_in[1];
    const float* sinp = (const float*)d_in[2];
    const float* Wq   = (const float*)d_in[3];
    const float* Wk   = (const float*)d_in[4];
    const float* Wv   = (const float*)d_in[5];
    const float* Wo   = (const float*)d_in[6];

    char* w = (char*)d_ws;
    ushort_t* xb     = (ushort_t*)w;                       w += (size_t)MROWS * D_MODEL * 2;
    ushort_t* WqkvT  = (ushort_t*)w;                       w += (size_t)QKVN * D_MODEL * 2;
    ushort_t* WoT    = (ushort_t*)w;                       w += (size_t)D_MODEL * D_MODEL * 2;
    ushort_t* QKVh   = (ushort_t*)w;                       w += (size_t)MROWS * QKVN * 2;
    ushort_t* Qbuf   = (ushort_t*)w;                       w += (size_t)MROWS * D_MODEL * 2;
    ushort_t* Kbuf   = (ushort_t*)w;                       w += (size_t)MROWS * KVDIM * 2;
    ushort_t* Vt     = (ushort_t*)w;                       w += (size_t)MROWS * KVDIM * 2;
    ushort_t* Obuf   = (ushort_t*)w;                       w += (size_t)MROWS * D_MODEL * 2;
    ushort_t* Pnum   = (ushort_t*)w;                       w += (size_t)NSPLIT * NTASK * 64 * 2;
    float*    Pl     = (float*)w;

    // --- prep: casts & weight transposes (all f16)
    cast_kernel<<<(MROWS * D_MODEL / 4 + 255) / 256, 256, 0, stream>>>(
        x, xb, MROWS * D_MODEL / 4);
    transpose_cast<<<dim3(D_MODEL / 32, D_MODEL / 32), 256, 0, stream>>>(
        Wq, WqkvT, D_MODEL, D_MODEL);
    transpose_cast<<<dim3(KVDIM / 32, D_MODEL / 32), 256, 0, stream>>>(
        Wk, WqkvT + (size_t)1024 * D_MODEL, D_MODEL, KVDIM);
    transpose_cast<<<dim3(KVDIM / 32, D_MODEL / 32), 256, 0, stream>>>(
        Wv, WqkvT + (size_t)1280 * D_MODEL, D_MODEL, KVDIM);
    transpose_cast<<<dim3(D_MODEL / 32, D_MODEL / 32), 256, 0, stream>>>(
        Wo, WoT, D_MODEL, D_MODEL);

    // --- fused QKV projection (f16 output)
    gemm_bt<<<dim3(QKVN / 128, MROWS / 128), 256, 0, stream>>>(
        xb, WqkvT, QKVh, MROWS, QKVN, D_MODEL, 1);

    // --- rope + relayout (Q,K), V transpose (all f16)
    rope_kernel<<<(NQW + NKW) / 256, 256, 0, stream>>>(QKVh, cosp, sinp, Qbuf, Kbuf);
    vtrans_kernel<<<dim3(NN / 32, KVDIM / 32, BB), 256, 0, stream>>>(QKVh, Vt);

    // --- attention (S^T f16, mt=4, split-K x4, normalized f16 partials)
    attn_mfma<<<dim3(NN / 256, NHEADS, BB * NSPLIT), 256, 0, stream>>>(
        Qbuf, Kbuf, Vt, Pnum, Pl);
    attn_combine<<<(NTASK * 16) / 256, 256, 0, stream>>>(Pnum, Pl, Obuf);

    // --- output projection (fp32 output)
    gemm_bt<<<dim3(D_MODEL / 128, MROWS / 128), 256, 0, stream>>>(
        Obuf, WoT, d_out, MROWS, D_MODEL, D_MODEL, 0);
}

// Round 12
// 216.608 us; speedup vs baseline: 1.2113x; 1.0199x over previous
//
#include <hip/hip_runtime.h>
#include <math.h>

#define D_MODEL 1024
#define NHEADS  16
#define NKV     4
#define HDIM    64
#define KVDIM   256
#define BB      2
#define NN      2048
#define MROWS   (BB*NN)        // 4096
#define QKVN    1536           // 1024 + 256 + 256
#define NTASK   (MROWS*NHEADS) // 65536
#define NSPLIT  4

typedef unsigned short ushort_t;
typedef unsigned int uint_t;
typedef float    f32x4 __attribute__((ext_vector_type(4)));
typedef _Float16 h16x8 __attribute__((ext_vector_type(8)));
typedef __fp16   fp16x2 __attribute__((ext_vector_type(2)));

#define MFMAH(A,B,C) __builtin_amdgcn_mfma_f32_16x16x32_f16((A),(B),(C),0,0,0)

// async global->LDS, 16B per lane; LDS dest = wave-uniform base + lane*16
#define GLDS(gp, lp) __builtin_amdgcn_global_load_lds( \
    (const __attribute__((address_space(1))) void*)(gp), \
    (__attribute__((address_space(3))) void*)(lp), 16, 0, 0)

__device__ __forceinline__ ushort_t f2h(float f) {
    _Float16 h = (_Float16)f;
    return *(ushort_t*)&h;
}
__device__ __forceinline__ float h2f(ushort_t u) {
    return (float)(*(const _Float16*)&u);
}
// two fp32 -> packed f16x2, single v_cvt_pkrtz_f16_f32
__device__ __forceinline__ uint_t pk2h(float a, float b) {
    fp16x2 v = __builtin_amdgcn_cvt_pkrtz(a, b);
    return *(uint_t*)&v;
}

// ---------------------------------------------------------------------------
// castx: fp32 -> f16, 4 elements/thread
// ---------------------------------------------------------------------------
__global__ __launch_bounds__(256)
void cast_kernel(const float* __restrict__ src, ushort_t* __restrict__ dst, int n4)
{
    int i = blockIdx.x * 256 + threadIdx.x;
    if (i >= n4) return;
    float4 v = ((const float4*)src)[i];
    uint2 o;
    o.x = pk2h(v.x, v.y);
    o.y = pk2h(v.z, v.w);
    ((uint2*)dst)[i] = o;
}

// ---------------------------------------------------------------------------
// transpose + cast: src fp32 [K][N] -> dst f16 [N][K]
// ---------------------------------------------------------------------------
__global__ __launch_bounds__(256)
void transpose_cast(const float* __restrict__ src, ushort_t* __restrict__ dst,
                    int K, int N)
{
    __shared__ float T[32][33];
    const int tx = threadIdx.x & 31, ty = threadIdx.x >> 5;
    const int n0 = blockIdx.x * 32, k0 = blockIdx.y * 32;
#pragma unroll
    for (int i = 0; i < 4; i++)
        T[ty + i * 8][tx] = src[(size_t)(k0 + ty + i * 8) * N + n0 + tx];
    __syncthreads();
#pragma unroll
    for (int i = 0; i < 4; i++)
        dst[(size_t)(n0 + ty + i * 8) * K + k0 + tx] = f2h(T[tx][ty + i * 8]);
}

// ---------------------------------------------------------------------------
// V transpose: QKVh (f16) cols [1280,1536) per batch -> Vt f16 [(b*256+d)][2048]
// ---------------------------------------------------------------------------
__global__ __launch_bounds__(256)
void vtrans_kernel(const ushort_t* __restrict__ QKVh, ushort_t* __restrict__ Vt)
{
    __shared__ ushort_t T[32][34];
    const int tx = threadIdx.x & 31, ty = threadIdx.x >> 5;
    const int n0 = blockIdx.x * 32, d0 = blockIdx.y * 32, b = blockIdx.z;
#pragma unroll
    for (int i = 0; i < 4; i++)
        T[ty + i * 8][tx] =
            QKVh[(size_t)(b * NN + n0 + ty + i * 8) * QKVN + 1280 + d0 + tx];
    __syncthreads();
#pragma unroll
    for (int i = 0; i < 4; i++)
        Vt[(size_t)(b * 256 + d0 + ty + i * 8) * NN + n0 + tx] = T[tx][ty + i * 8];
}

// ---------------------------------------------------------------------------
// RoPE (f16 in/out) + relayout for Q and K.
// Q gets 0.125*log2(e) folded in (softmax runs base-2).
// ---------------------------------------------------------------------------
#define NQW (MROWS*NHEADS*32)   // 2,097,152
#define NKW (MROWS*NKV*32)      //   524,288
__global__ __launch_bounds__(256)
void rope_kernel(const ushort_t* __restrict__ QKVh, const float* __restrict__ Cos,
                 const float* __restrict__ Sin, ushort_t* __restrict__ Qb,
                 ushort_t* __restrict__ Kb)
{
    const float SC = 0.125f * 1.44269504f;
    int idx = blockIdx.x * 256 + threadIdx.x;
    if (idx < NQW) {
        const int row = idx >> 9, rem = idx & 511;
        const int h = rem >> 5, j = rem & 31;
        const int b = row >> 11, n = row & (NN - 1);
        const uint_t pr = *(const uint_t*)&QKVh[(size_t)row * QKVN + h * 64 + 2 * j];
        const float e = h2f((ushort_t)pr), o = h2f((ushort_t)(pr >> 16));
        const float c = Cos[n * 32 + j], s = Sin[n * 32 + j];
        ushort_t* dst = Qb + ((size_t)(b * 16 + h) * NN + n) * 64;
        dst[j]      = f2h((e * c - o * s) * SC);
        dst[j + 32] = f2h((e * s + o * c) * SC);
    } else {
        const int i2 = idx - NQW;
        const int row = i2 >> 7, rem = i2 & 127;
        const int h = rem >> 5, j = rem & 31;
        const int b = row >> 11, n = row & (NN - 1);
        const uint_t pr = *(const uint_t*)&QKVh[(size_t)row * QKVN + 1024 + h * 64 + 2 * j];
        const float e = h2f((ushort_t)pr), o = h2f((ushort_t)(pr >> 16));
        const float c = Cos[n * 32 + j], s = Sin[n * 32 + j];
        ushort_t* dst = Kb + ((size_t)(b * 4 + h) * NN + n) * 64;
        dst[j]      = f2h(e * c - o * s);
        dst[j + 32] = f2h(e * s + o * c);
    }
}

// ---------------------------------------------------------------------------
// f16 MFMA GEMM v2: 128x64 tile (M x N) for 2-3x more blocks (grid was
// starving 256 CUs at 128x128: Wo had exactly 1 block/CU -> all latency
// exposed). GLDS + XOR swizzle + double-buffered LDS, one barrier/iter.
// 4 waves in 2x2: wave tile 64x32 (mt=4, nt=2). LDS 2*(8K+4K)=24 KB.
// halfout: 1 -> C f16, else fp32.
// ---------------------------------------------------------------------------
__global__ __launch_bounds__(256)
void gemm_bt(const ushort_t* __restrict__ A, const ushort_t* __restrict__ Bt,
             void* __restrict__ C, int M, int N, int K, int halfout)
{
    __shared__ ushort_t As[2][128 * 32];
    __shared__ ushort_t Bs[2][64 * 32];

    const int tid  = threadIdx.x;
    const int wave = tid >> 6, lane = tid & 63;
    const int quad = lane >> 4, l16 = lane & 15;
    const int rowBase = blockIdx.y * 128, colBase = blockIdx.x * 64;
    const int wm = (wave >> 1) * 64, wn = (wave & 1) * 32;

    f32x4 acc[4][2];
    const f32x4 zz = {0.f, 0.f, 0.f, 0.f};
#pragma unroll
    for (int i = 0; i < 4; i++)
#pragma unroll
        for (int j = 0; j < 2; j++) acc[i][j] = zz;

    // A staging (128 rows, 2 GLDS rounds of 64 rows):
    // lane l -> row seg + l>>2, stored 16B block (l&3)^((l>>3)&3)
    const int sr = wave * 32 + (lane >> 2);
    const int sc = ((lane & 3) ^ ((lane >> 3) & 3)) * 8;
    const ushort_t* Ag0 = A + (size_t)(rowBase + sr) * K + sc;
    const ushort_t* Ag1 = A + (size_t)(rowBase + sr + 16) * K + sc;
    const int segA0 = (wave * 2 + 0) * 512, segA1 = (wave * 2 + 1) * 512;
    // B staging (64 rows, 1 GLDS round): wave covers 16 rows
    const int br = wave * 16 + (lane >> 2);
    const ushort_t* Bg0 = Bt + (size_t)(colBase + br) * K + sc;
    const int segB = wave * 512;

    // frag-read swizzled column
    const int fcol = (quad ^ ((l16 >> 1) & 3)) * 8;

    // prologue: stage tile 0 into buffer 0
    GLDS(Ag0, &As[0][segA0]);
    GLDS(Ag1, &As[0][segA1]);
    GLDS(Bg0, &Bs[0][segB]);

    for (int k0 = 0; k0 < K; k0 += 32) {
        const int cur = (k0 >> 5) & 1, nxt = cur ^ 1;
        __syncthreads();   // drains staging for buf[cur]; frees buf[nxt]
        if (k0 + 32 < K) {
            GLDS(Ag0 + k0 + 32, &As[nxt][segA0]);
            GLDS(Ag1 + k0 + 32, &As[nxt][segA1]);
            GLDS(Bg0 + k0 + 32, &Bs[nxt][segB]);
        }

        h16x8 af[4], bf[2];
#pragma unroll
        for (int mt = 0; mt < 4; mt++)
            af[mt] = *(const h16x8*)&As[cur][(wm + mt * 16 + l16) * 32 + fcol];
#pragma unroll
        for (int nt = 0; nt < 2; nt++)
            bf[nt] = *(const h16x8*)&Bs[cur][(wn + nt * 16 + l16) * 32 + fcol];
#pragma unroll
        for (int mt = 0; mt < 4; mt++)
#pragma unroll
            for (int nt = 0; nt < 2; nt++)
                acc[mt][nt] = MFMAH(af[mt], bf[nt], acc[mt][nt]);
    }

    if (halfout) {
        ushort_t* Ch = (ushort_t*)C;
#pragma unroll
        for (int mt = 0; mt < 4; mt++)
#pragma unroll
            for (int nt = 0; nt < 2; nt++) {
                const int row = rowBase + wm + mt * 16 + quad * 4;
                const int col = colBase + wn + nt * 16 + l16;
#pragma unroll
                for (int r = 0; r < 4; r++)
                    Ch[(size_t)(row + r) * N + col] = f2h(acc[mt][nt][r]);
            }
    } else {
        float* Cf = (float*)C;
#pragma unroll
        for (int mt = 0; mt < 4; mt++)
#pragma unroll
            for (int nt = 0; nt < 2; nt++) {
                const int row = rowBase + wm + mt * 16 + quad * 4;
                const int col = colBase + wn + nt * 16 + l16;
#pragma unroll
                for (int r = 0; r < 4; r++)
                    Cf[(size_t)(row + r) * N + col] = acc[mt][nt][r];
            }
    }
}

// ---------------------------------------------------------------------------
// MFMA flash attention v7 (unchanged from round 11): S^T form, f16, mt=4,
// slot-reuse P, split-K x4, no-max softmax, normalized f16 partials.
// ---------------------------------------------------------------------------
__global__ __launch_bounds__(256)
void attn_mfma(const ushort_t* __restrict__ Qb, const ushort_t* __restrict__ Kb,
               const ushort_t* __restrict__ Vt, ushort_t* __restrict__ Pnum,
               float* __restrict__ Pl)
{
    const int qt = blockIdx.x, h = blockIdx.y;
    const int b = blockIdx.z >> 2, chunk = blockIdx.z & 3;
    const int kvh = h >> 2;
    const int tid = threadIdx.x;
    const int wave = tid >> 6, lane = tid & 63;
    const int quad = lane >> 4, l16 = lane & 15;

    __shared__ ushort_t Ks[64][72];
    __shared__ ushort_t Vs[64][72];
    __shared__ ushort_t Ps[4][16 * 72];
    ushort_t* ps = &Ps[wave][0];

    const int row0 = qt * 256 + wave * 64;
    h16x8 qf[4][2];
#pragma unroll
    for (int mt = 0; mt < 4; mt++) {
        const ushort_t* qp =
            Qb + ((size_t)(b * 16 + h) * NN + row0 + mt * 16 + l16) * 64 + quad * 8;
        qf[mt][0] = *(const h16x8*)qp;
        qf[mt][1] = *(const h16x8*)(qp + 32);
    }

    const ushort_t* kbase = Kb + (size_t)(b * 4 + kvh) * NN * 64;
    const ushort_t* vbase = Vt + (size_t)(b * 256 + kvh * 64) * NN;
    const int key_lo = chunk * (NN / NSPLIT);
    const int rot = (qt + ((h & 3) << 1)) & 7;

    const int srow = tid >> 2, sseg = (tid & 3) * 8;

    const f32x4 zz = {0.f, 0.f, 0.f, 0.f};
    f32x4 o[4][4];
#pragma unroll
    for (int mt = 0; mt < 4; mt++)
#pragma unroll
        for (int dt = 0; dt < 4; dt++) o[mt][dt] = zz;
    float lacc[4] = {0.f, 0.f, 0.f, 0.f};

    int key0 = key_lo + rot * 64;
    const ushort_t* kp0 = kbase + (size_t)(key0 + srow) * 64 + sseg;
    const ushort_t* vp0 = vbase + (size_t)srow * NN + key0 + sseg;
    uint4 kreg0 = *(const uint4*)kp0;
    uint4 kreg1 = *(const uint4*)(kp0 + 32);
    uint4 vreg0 = *(const uint4*)vp0;
    uint4 vreg1 = *(const uint4*)(vp0 + 32);

    for (int t = 0; t < 8; t++) {
        __syncthreads();
        *(uint4*)&Ks[srow][sseg]      = kreg0;
        *(uint4*)&Ks[srow][sseg + 32] = kreg1;
        *(uint4*)&Vs[srow][sseg]      = vreg0;
        *(uint4*)&Vs[srow][sseg + 32] = vreg1;
        __syncthreads();

        if (t < 7) {
            const int kn = key_lo + ((rot + t + 1) & 7) * 64;
            const ushort_t* kpn = kbase + (size_t)(kn + srow) * 64 + sseg;
            const ushort_t* vpn = vbase + (size_t)srow * NN + kn + sseg;
            kreg0 = *(const uint4*)kpn;
            kreg1 = *(const uint4*)(kpn + 32);
            vreg0 = *(const uint4*)vpn;
            vreg1 = *(const uint4*)(vpn + 32);
        }

        // ---- Phase 1: S^T = K Q^T; exp2 + pack to registers
        uint2 pkreg[4][4];
#pragma unroll
        for (int kt = 0; kt < 4; kt++) {
            h16x8 kf0 = *(const h16x8*)&Ks[kt * 16 + l16][quad * 8];
            h16x8 kf1 = *(const h16x8*)&Ks[kt * 16 + l16][32 + quad * 8];
#pragma unroll
            for (int mt = 0; mt < 4; mt++) {
                f32x4 st = MFMAH(kf0, qf[mt][0], zz);
                st = MFMAH(kf1, qf[mt][1], st);
                const float p0 = exp2f(st[0]);
                const float p1 = exp2f(st[1]);
                const float p2 = exp2f(st[2]);
                const float p3 = exp2f(st[3]);
                lacc[mt] += (p0 + p1) + (p2 + p3);
                pkreg[kt][mt].x = pk2h(p0, p1);
                pkreg[kt][mt].y = pk2h(p2, p3);
            }
        }

        // ---- Phase 2: per mt: write P^T slot, read A-frags, PV MFMAs
        h16x8 vf[4][2];
#pragma unroll
        for (int dt = 0; dt < 4; dt++) {
            vf[dt][0] = *(const h16x8*)&Vs[dt * 16 + l16][quad * 8];
            vf[dt][1] = *(const h16x8*)&Vs[dt * 16 + l16][32 + quad * 8];
        }
#pragma unroll
        for (int mt = 0; mt < 4; mt++) {
#pragma unroll
            for (int kt = 0; kt < 4; kt++)
                *(uint2*)&ps[l16 * 72 + kt * 16 + quad * 4] = pkreg[kt][mt];
            h16x8 pa0 = *(const h16x8*)&ps[l16 * 72 + quad * 8];
            h16x8 pa1 = *(const h16x8*)&ps[l16 * 72 + 32 + quad * 8];
#pragma unroll
            for (int dt = 0; dt < 4; dt++) {
                o[mt][dt] = MFMAH(vf[dt][0], pa0, o[mt][dt]);
                o[mt][dt] = MFMAH(vf[dt][1], pa1, o[mt][dt]);
            }
        }
    }

#pragma unroll
    for (int mt = 0; mt < 4; mt++) {
        lacc[mt] += __shfl_xor(lacc[mt], 16, 64);
        lacc[mt] += __shfl_xor(lacc[mt], 32, 64);
    }

    const size_t task0 = (size_t)(b * 16 + h) * NN + row0;
    ushort_t* np = Pnum + ((size_t)chunk * NTASK + task0) * 64;
#pragma unroll
    for (int mt = 0; mt < 4; mt++) {
        const float inv = 1.0f / lacc[mt];
#pragma unroll
        for (int dt = 0; dt < 4; dt++) {
            f32x4 v = o[mt][dt];
            uint2 pk;
            pk.x = pk2h(v[0] * inv, v[1] * inv);
            pk.y = pk2h(v[2] * inv, v[3] * inv);
            *(uint2*)&np[(size_t)(mt * 16 + l16) * 64 + dt * 16 + quad * 4] = pk;
        }
        if (quad == 0)
            Pl[(size_t)chunk * NTASK + task0 + mt * 16 + l16] = lacc[mt];
    }
}

// ---------------------------------------------------------------------------
// Combine: O = sum(l_s * ohat_s) / sum(l_s), f16 in/out.
// ---------------------------------------------------------------------------
__global__ __launch_bounds__(256)
void attn_combine(const ushort_t* __restrict__ Pnum, const float* __restrict__ Pl,
                  ushort_t* __restrict__ Ob)
{
    const int gid  = blockIdx.x * 256 + threadIdx.x;
    const int task = gid >> 4;
    const int d    = (gid & 15) * 4;
    float a0 = 0.f, a1 = 0.f, a2 = 0.f, a3 = 0.f, lsum = 0.f;
#pragma unroll
    for (int s = 0; s < NSPLIT; s++) {
        const uint2 pk = *(const uint2*)&Pnum[((size_t)s * NTASK + task) * 64 + d];
        const float l = Pl[(size_t)s * NTASK + task];
        const fp16x2 lo = *(const fp16x2*)&pk.x;
        const fp16x2 hi = *(const fp16x2*)&pk.y;
        a0 += l * (float)lo.x; a1 += l * (float)lo.y;
        a2 += l * (float)hi.x; a3 += l * (float)hi.y;
        lsum += l;
    }
    const float inv = 1.0f / lsum;
    const int n = task & (NN - 1), bh = task >> 11;
    const int h = bh & (NHEADS - 1), b = bh >> 4;
    ushort_t* op = Ob + (size_t)(b * NN + n) * D_MODEL + h * 64 + d;
    uint2 o2;
    o2.x = pk2h(a0 * inv, a1 * inv);
    o2.y = pk2h(a2 * inv, a3 * inv);
    *(uint2*)op = o2;
}

// ---------------------------------------------------------------------------
extern "C" void kernel_launch(void* const* d_in, const int* in_sizes, int n_in,
                              void* d_out, int out_size, void* d_ws, size_t ws_size,
                              hipStream_t stream)
{
    const float* x    = (const float*)d_in[0];
    const float* cosp = (const float*)d_in[1];
    const float* sinp = (const float*)d_in[2];
    const float* Wq   = (const float*)d_in[3];
    const float* Wk   = (const float*)d_in[4];
    const float* Wv   = (const float*)d_in[5];
    const float* Wo   = (const float*)d_in[6];

    char* w = (char*)d_ws;
    ushort_t* xb     = (ushort_t*)w;                       w += (size_t)MROWS * D_MODEL * 2;
    ushort_t* WqkvT  = (ushort_t*)w;                       w += (size_t)QKVN * D_MODEL * 2;
    ushort_t* WoT    = (ushort_t*)w;                       w += (size_t)D_MODEL * D_MODEL * 2;
    ushort_t* QKVh   = (ushort_t*)w;                       w += (size_t)MROWS * QKVN * 2;
    ushort_t* Qbuf   = (ushort_t*)w;                       w += (size_t)MROWS * D_MODEL * 2;
    ushort_t* Kbuf   = (ushort_t*)w;                       w += (size_t)MROWS * KVDIM * 2;
    ushort_t* Vt     = (ushort_t*)w;                       w += (size_t)MROWS * KVDIM * 2;
    ushort_t* Obuf   = (ushort_t*)w;                       w += (size_t)MROWS * D_MODEL * 2;
    ushort_t* Pnum   = (ushort_t*)w;                       w += (size_t)NSPLIT * NTASK * 64 * 2;
    float*    Pl     = (float*)w;

    // --- prep: casts & weight transposes (all f16)
    cast_kernel<<<(MROWS * D_MODEL / 4 + 255) / 256, 256, 0, stream>>>(
        x, xb, MROWS * D_MODEL / 4);
    transpose_cast<<<dim3(D_MODEL / 32, D_MODEL / 32), 256, 0, stream>>>(
        Wq, WqkvT, D_MODEL, D_MODEL);
    transpose_cast<<<dim3(KVDIM / 32, D_MODEL / 32), 256, 0, stream>>>(
        Wk, WqkvT + (size_t)1024 * D_MODEL, D_MODEL, KVDIM);
    transpose_cast<<<dim3(KVDIM / 32, D_MODEL / 32), 256, 0, stream>>>(
        Wv, WqkvT + (size_t)1280 * D_MODEL, D_MODEL, KVDIM);
    transpose_cast<<<dim3(D_MODEL / 32, D_MODEL / 32), 256, 0, stream>>>(
        Wo, WoT, D_MODEL, D_MODEL);

    // --- fused QKV projection (f16 output), 128x64 tiles -> 768 blocks
    gemm_bt<<<dim3(QKVN / 64, MROWS / 128), 256, 0, stream>>>(
        xb, WqkvT, QKVh, MROWS, QKVN, D_MODEL, 1);

    // --- rope + relayout (Q,K), V transpose (all f16)
    rope_kernel<<<(NQW + NKW) / 256, 256, 0, stream>>>(QKVh, cosp, sinp, Qbuf, Kbuf);
    vtrans_kernel<<<dim3(NN / 32, KVDIM / 32, BB), 256, 0, stream>>>(QKVh, Vt);

    // --- attention (S^T f16, mt=4, split-K x4, normalized f16 partials)
    attn_mfma<<<dim3(NN / 256, NHEADS, BB * NSPLIT), 256, 0, stream>>>(
        Qbuf, Kbuf, Vt, Pnum, Pl);
    attn_combine<<<(NTASK * 16) / 256, 256, 0, stream>>>(Pnum, Pl, Obuf);

    // --- output projection (fp32 output), 128x64 tiles -> 512 blocks
    gemm_bt<<<dim3(D_MODEL / 64, MROWS / 128), 256, 0, stream>>>(
        Obuf, WoT, d_out, MROWS, D_MODEL, D_MODEL, 0);
}

// Round 13
// 215.428 us; speedup vs baseline: 1.2179x; 1.0055x over previous
//
#include <hip/hip_runtime.h>
#include <math.h>

#define D_MODEL 1024
#define NHEADS  16
#define NKV     4
#define HDIM    64
#define KVDIM   256
#define BB      2
#define NN      2048
#define MROWS   (BB*NN)        // 4096
#define QKVN    1536           // 1024 + 256 + 256
#define NTASK   (MROWS*NHEADS) // 65536
#define NSPLIT  2

typedef unsigned short ushort_t;
typedef unsigned int uint_t;
typedef float    f32x4 __attribute__((ext_vector_type(4)));
typedef _Float16 h16x8 __attribute__((ext_vector_type(8)));
typedef __fp16   fp16x2 __attribute__((ext_vector_type(2)));

#define MFMAH(A,B,C) __builtin_amdgcn_mfma_f32_16x16x32_f16((A),(B),(C),0,0,0)

// async global->LDS, 16B per lane; LDS dest = wave-uniform base + lane*16
#define GLDS(gp, lp) __builtin_amdgcn_global_load_lds( \
    (const __attribute__((address_space(1))) void*)(gp), \
    (__attribute__((address_space(3))) void*)(lp), 16, 0, 0)

__device__ __forceinline__ ushort_t f2h(float f) {
    _Float16 h = (_Float16)f;
    return *(ushort_t*)&h;
}
__device__ __forceinline__ float h2f(ushort_t u) {
    return (float)(*(const _Float16*)&u);
}
// two fp32 -> packed f16x2, single v_cvt_pkrtz_f16_f32
__device__ __forceinline__ uint_t pk2h(float a, float b) {
    fp16x2 v = __builtin_amdgcn_cvt_pkrtz(a, b);
    return *(uint_t*)&v;
}

// ---------------------------------------------------------------------------
// Fused prep: cast x->f16 (blocks [0,4096)) + 4 weight transpose-casts
// (blocks [4096,6656)). One dispatch instead of five.
// ---------------------------------------------------------------------------
__global__ __launch_bounds__(256)
void prep_kernel(const float* __restrict__ x, const float* __restrict__ Wq,
                 const float* __restrict__ Wk, const float* __restrict__ Wv,
                 const float* __restrict__ Wo, ushort_t* __restrict__ xb,
                 ushort_t* __restrict__ WqkvT, ushort_t* __restrict__ WoT)
{
    __shared__ float T[32][33];
    int blk = blockIdx.x;
    if (blk < 4096) {                      // cast: 4096*256*4 = 4M elements
        const int i = blk * 256 + threadIdx.x;
        float4 v = ((const float4*)x)[i];
        uint2 o;
        o.x = pk2h(v.x, v.y);
        o.y = pk2h(v.z, v.w);
        ((uint2*)xb)[i] = o;
        return;
    }
    blk -= 4096;
    const float* src; ushort_t* dst; int N, bx, by;
    if (blk < 1024)      { src = Wq; dst = WqkvT;                            N = D_MODEL; bx = blk & 31; by = blk >> 5; }
    else if (blk < 1280) { blk -= 1024; src = Wk; dst = WqkvT + (size_t)1024 * D_MODEL; N = KVDIM; bx = blk & 7; by = blk >> 3; }
    else if (blk < 1536) { blk -= 1280; src = Wv; dst = WqkvT + (size_t)1280 * D_MODEL; N = KVDIM; bx = blk & 7; by = blk >> 3; }
    else                 { blk -= 1536; src = Wo; dst = WoT;                 N = D_MODEL; bx = blk & 31; by = blk >> 5; }
    const int tx = threadIdx.x & 31, ty = threadIdx.x >> 5;
    const int n0 = bx * 32, k0 = by * 32;
#pragma unroll
    for (int i = 0; i < 4; i++)
        T[ty + i * 8][tx] = src[(size_t)(k0 + ty + i * 8) * N + n0 + tx];
    __syncthreads();
#pragma unroll
    for (int i = 0; i < 4; i++)
        dst[(size_t)(n0 + ty + i * 8) * D_MODEL + k0 + tx] = f2h(T[tx][ty + i * 8]);
}

// ---------------------------------------------------------------------------
// V transpose: QKVh (f16) cols [1280,1536) per batch -> Vt f16 [(b*256+d)][2048]
// ---------------------------------------------------------------------------
__global__ __launch_bounds__(256)
void vtrans_kernel(const ushort_t* __restrict__ QKVh, ushort_t* __restrict__ Vt)
{
    __shared__ ushort_t T[32][34];
    const int tx = threadIdx.x & 31, ty = threadIdx.x >> 5;
    const int n0 = blockIdx.x * 32, d0 = blockIdx.y * 32, b = blockIdx.z;
#pragma unroll
    for (int i = 0; i < 4; i++)
        T[ty + i * 8][tx] =
            QKVh[(size_t)(b * NN + n0 + ty + i * 8) * QKVN + 1280 + d0 + tx];
    __syncthreads();
#pragma unroll
    for (int i = 0; i < 4; i++)
        Vt[(size_t)(b * 256 + d0 + ty + i * 8) * NN + n0 + tx] = T[tx][ty + i * 8];
}

// ---------------------------------------------------------------------------
// RoPE (f16 in/out) + relayout for Q and K. Q gets 0.125*log2(e) folded in.
// ---------------------------------------------------------------------------
#define NQW (MROWS*NHEADS*32)   // 2,097,152
#define NKW (MROWS*NKV*32)      //   524,288
__global__ __launch_bounds__(256)
void rope_kernel(const ushort_t* __restrict__ QKVh, const float* __restrict__ Cos,
                 const float* __restrict__ Sin, ushort_t* __restrict__ Qb,
                 ushort_t* __restrict__ Kb)
{
    const float SC = 0.125f * 1.44269504f;
    int idx = blockIdx.x * 256 + threadIdx.x;
    if (idx < NQW) {
        const int row = idx >> 9, rem = idx & 511;
        const int h = rem >> 5, j = rem & 31;
        const int b = row >> 11, n = row & (NN - 1);
        const uint_t pr = *(const uint_t*)&QKVh[(size_t)row * QKVN + h * 64 + 2 * j];
        const float e = h2f((ushort_t)pr), o = h2f((ushort_t)(pr >> 16));
        const float c = Cos[n * 32 + j], s = Sin[n * 32 + j];
        ushort_t* dst = Qb + ((size_t)(b * 16 + h) * NN + n) * 64;
        dst[j]      = f2h((e * c - o * s) * SC);
        dst[j + 32] = f2h((e * s + o * c) * SC);
    } else {
        const int i2 = idx - NQW;
        const int row = i2 >> 7, rem = i2 & 127;
        const int h = rem >> 5, j = rem & 31;
        const int b = row >> 11, n = row & (NN - 1);
        const uint_t pr = *(const uint_t*)&QKVh[(size_t)row * QKVN + 1024 + h * 64 + 2 * j];
        const float e = h2f((ushort_t)pr), o = h2f((ushort_t)(pr >> 16));
        const float c = Cos[n * 32 + j], s = Sin[n * 32 + j];
        ushort_t* dst = Kb + ((size_t)(b * 4 + h) * NN + n) * 64;
        dst[j]      = f2h(e * c - o * s);
        dst[j + 32] = f2h(e * s + o * c);
    }
}

// ---------------------------------------------------------------------------
// f16 MFMA GEMM for QKV (f16 out), 128x64 tile, GLDS + XOR swizzle +
// double-buffered LDS, one barrier/iter (round-12 structure).
// ---------------------------------------------------------------------------
__global__ __launch_bounds__(256)
void gemm_qkv(const ushort_t* __restrict__ A, const ushort_t* __restrict__ Bt,
              ushort_t* __restrict__ C, int M, int N, int K)
{
    __shared__ ushort_t As[2][128 * 32];
    __shared__ ushort_t Bs[2][64 * 32];

    const int tid  = threadIdx.x;
    const int wave = tid >> 6, lane = tid & 63;
    const int quad = lane >> 4, l16 = lane & 15;
    const int rowBase = blockIdx.y * 128, colBase = blockIdx.x * 64;
    const int wm = (wave >> 1) * 64, wn = (wave & 1) * 32;

    f32x4 acc[4][2];
    const f32x4 zz = {0.f, 0.f, 0.f, 0.f};
#pragma unroll
    for (int i = 0; i < 4; i++)
#pragma unroll
        for (int j = 0; j < 2; j++) acc[i][j] = zz;

    const int sr = wave * 32 + (lane >> 2);
    const int sc = ((lane & 3) ^ ((lane >> 3) & 3)) * 8;
    const ushort_t* Ag0 = A + (size_t)(rowBase + sr) * K + sc;
    const ushort_t* Ag1 = A + (size_t)(rowBase + sr + 16) * K + sc;
    const int segA0 = (wave * 2 + 0) * 512, segA1 = (wave * 2 + 1) * 512;
    const int br = wave * 16 + (lane >> 2);
    const ushort_t* Bg0 = Bt + (size_t)(colBase + br) * K + sc;
    const int segB = wave * 512;

    const int fcol = (quad ^ ((l16 >> 1) & 3)) * 8;

    GLDS(Ag0, &As[0][segA0]);
    GLDS(Ag1, &As[0][segA1]);
    GLDS(Bg0, &Bs[0][segB]);

    for (int k0 = 0; k0 < K; k0 += 32) {
        const int cur = (k0 >> 5) & 1, nxt = cur ^ 1;
        __syncthreads();
        if (k0 + 32 < K) {
            GLDS(Ag0 + k0 + 32, &As[nxt][segA0]);
            GLDS(Ag1 + k0 + 32, &As[nxt][segA1]);
            GLDS(Bg0 + k0 + 32, &Bs[nxt][segB]);
        }

        h16x8 af[4], bf[2];
#pragma unroll
        for (int mt = 0; mt < 4; mt++)
            af[mt] = *(const h16x8*)&As[cur][(wm + mt * 16 + l16) * 32 + fcol];
#pragma unroll
        for (int nt = 0; nt < 2; nt++)
            bf[nt] = *(const h16x8*)&Bs[cur][(wn + nt * 16 + l16) * 32 + fcol];
#pragma unroll
        for (int mt = 0; mt < 4; mt++)
#pragma unroll
            for (int nt = 0; nt < 2; nt++)
                acc[mt][nt] = MFMAH(af[mt], bf[nt], acc[mt][nt]);
    }

#pragma unroll
    for (int mt = 0; mt < 4; mt++)
#pragma unroll
        for (int nt = 0; nt < 2; nt++) {
            const int row = rowBase + wm + mt * 16 + quad * 4;
            const int col = colBase + wn + nt * 16 + l16;
#pragma unroll
            for (int r = 0; r < 4; r++)
                C[(size_t)(row + r) * N + col] = f2h(acc[mt][nt][r]);
        }
}

// ---------------------------------------------------------------------------
// MFMA flash attention (round-11 core), NSPLIT=2: 1024 keys/block in 16
// tiles. S^T form, f16, mt=4, slot-reuse P, no-max softmax, rotated start,
// normalized f16 partials.
// ---------------------------------------------------------------------------
__global__ __launch_bounds__(256)
void attn_mfma(const ushort_t* __restrict__ Qb, const ushort_t* __restrict__ Kb,
               const ushort_t* __restrict__ Vt, ushort_t* __restrict__ Pnum,
               float* __restrict__ Pl)
{
    const int qt = blockIdx.x, h = blockIdx.y;
    const int b = blockIdx.z >> 1, chunk = blockIdx.z & 1;
    const int kvh = h >> 2;
    const int tid = threadIdx.x;
    const int wave = tid >> 6, lane = tid & 63;
    const int quad = lane >> 4, l16 = lane & 15;

    __shared__ ushort_t Ks[64][72];
    __shared__ ushort_t Vs[64][72];
    __shared__ ushort_t Ps[4][16 * 72];
    ushort_t* ps = &Ps[wave][0];

    const int row0 = qt * 256 + wave * 64;
    h16x8 qf[4][2];
#pragma unroll
    for (int mt = 0; mt < 4; mt++) {
        const ushort_t* qp =
            Qb + ((size_t)(b * 16 + h) * NN + row0 + mt * 16 + l16) * 64 + quad * 8;
        qf[mt][0] = *(const h16x8*)qp;
        qf[mt][1] = *(const h16x8*)(qp + 32);
    }

    const ushort_t* kbase = Kb + (size_t)(b * 4 + kvh) * NN * 64;
    const ushort_t* vbase = Vt + (size_t)(b * 256 + kvh * 64) * NN;
    const int key_lo = chunk * (NN / NSPLIT);          // 1024-key chunk
    const int rot = (qt + ((h & 3) << 2)) & 15;

    const int srow = tid >> 2, sseg = (tid & 3) * 8;

    const f32x4 zz = {0.f, 0.f, 0.f, 0.f};
    f32x4 o[4][4];
#pragma unroll
    for (int mt = 0; mt < 4; mt++)
#pragma unroll
        for (int dt = 0; dt < 4; dt++) o[mt][dt] = zz;
    float lacc[4] = {0.f, 0.f, 0.f, 0.f};

    int key0 = key_lo + rot * 64;
    const ushort_t* kp0 = kbase + (size_t)(key0 + srow) * 64 + sseg;
    const ushort_t* vp0 = vbase + (size_t)srow * NN + key0 + sseg;
    uint4 kreg0 = *(const uint4*)kp0;
    uint4 kreg1 = *(const uint4*)(kp0 + 32);
    uint4 vreg0 = *(const uint4*)vp0;
    uint4 vreg1 = *(const uint4*)(vp0 + 32);

    for (int t = 0; t < 16; t++) {
        __syncthreads();
        *(uint4*)&Ks[srow][sseg]      = kreg0;
        *(uint4*)&Ks[srow][sseg + 32] = kreg1;
        *(uint4*)&Vs[srow][sseg]      = vreg0;
        *(uint4*)&Vs[srow][sseg + 32] = vreg1;
        __syncthreads();

        if (t < 15) {
            const int kn = key_lo + ((rot + t + 1) & 15) * 64;
            const ushort_t* kpn = kbase + (size_t)(kn + srow) * 64 + sseg;
            const ushort_t* vpn = vbase + (size_t)srow * NN + kn + sseg;
            kreg0 = *(const uint4*)kpn;
            kreg1 = *(const uint4*)(kpn + 32);
            vreg0 = *(const uint4*)vpn;
            vreg1 = *(const uint4*)(vpn + 32);
        }

        // ---- Phase 1: S^T = K Q^T; exp2 + pack to registers
        uint2 pkreg[4][4];
#pragma unroll
        for (int kt = 0; kt < 4; kt++) {
            h16x8 kf0 = *(const h16x8*)&Ks[kt * 16 + l16][quad * 8];
            h16x8 kf1 = *(const h16x8*)&Ks[kt * 16 + l16][32 + quad * 8];
#pragma unroll
            for (int mt = 0; mt < 4; mt++) {
                f32x4 st = MFMAH(kf0, qf[mt][0], zz);
                st = MFMAH(kf1, qf[mt][1], st);
                const float p0 = exp2f(st[0]);
                const float p1 = exp2f(st[1]);
                const float p2 = exp2f(st[2]);
                const float p3 = exp2f(st[3]);
                lacc[mt] += (p0 + p1) + (p2 + p3);
                pkreg[kt][mt].x = pk2h(p0, p1);
                pkreg[kt][mt].y = pk2h(p2, p3);
            }
        }

        // ---- Phase 2: per mt: write P^T slot, read A-frags, PV MFMAs
        h16x8 vf[4][2];
#pragma unroll
        for (int dt = 0; dt < 4; dt++) {
            vf[dt][0] = *(const h16x8*)&Vs[dt * 16 + l16][quad * 8];
            vf[dt][1] = *(const h16x8*)&Vs[dt * 16 + l16][32 + quad * 8];
        }
#pragma unroll
        for (int mt = 0; mt < 4; mt++) {
#pragma unroll
            for (int kt = 0; kt < 4; kt++)
                *(uint2*)&ps[l16 * 72 + kt * 16 + quad * 4] = pkreg[kt][mt];
            h16x8 pa0 = *(const h16x8*)&ps[l16 * 72 + quad * 8];
            h16x8 pa1 = *(const h16x8*)&ps[l16 * 72 + 32 + quad * 8];
#pragma unroll
            for (int dt = 0; dt < 4; dt++) {
                o[mt][dt] = MFMAH(vf[dt][0], pa0, o[mt][dt]);
                o[mt][dt] = MFMAH(vf[dt][1], pa1, o[mt][dt]);
            }
        }
    }

#pragma unroll
    for (int mt = 0; mt < 4; mt++) {
        lacc[mt] += __shfl_xor(lacc[mt], 16, 64);
        lacc[mt] += __shfl_xor(lacc[mt], 32, 64);
    }

    const size_t task0 = (size_t)(b * 16 + h) * NN + row0;
    ushort_t* np = Pnum + ((size_t)chunk * NTASK + task0) * 64;
#pragma unroll
    for (int mt = 0; mt < 4; mt++) {
        const float inv = 1.0f / lacc[mt];
#pragma unroll
        for (int dt = 0; dt < 4; dt++) {
            f32x4 v = o[mt][dt];
            uint2 pk;
            pk.x = pk2h(v[0] * inv, v[1] * inv);
            pk.y = pk2h(v[2] * inv, v[3] * inv);
            *(uint2*)&np[(size_t)(mt * 16 + l16) * 64 + dt * 16 + quad * 4] = pk;
        }
        if (quad == 0)
            Pl[(size_t)chunk * NTASK + task0 + mt * 16 + l16] = lacc[mt];
    }
}

// ---------------------------------------------------------------------------
// Wo GEMM with FUSED split-K combine: A[r][c] = (l0*ohat0 + l1*ohat1)/(l0+l1)
// computed during A-tile staging (manual ds_write into padded stride-40 LDS,
// 2 barriers/iter); B staged via GLDS + XOR swizzle, double-buffered.
// 128x64 tile, fp32 out. Deletes the combine kernel + Obuf round-trip.
// ---------------------------------------------------------------------------
__global__ __launch_bounds__(256)
void gemm_wo(const ushort_t* __restrict__ Pnum, const float* __restrict__ Pl,
             const ushort_t* __restrict__ WoT, float* __restrict__ C)
{
    __shared__ ushort_t As[2][128 * 40];   // padded rows: conflict-free b128
    __shared__ ushort_t Bs[2][64 * 32];

    const int tid  = threadIdx.x;
    const int wave = tid >> 6, lane = tid & 63;
    const int quad = lane >> 4, l16 = lane & 15;
    const int rowBase = blockIdx.y * 128, colBase = blockIdx.x * 64;
    const int wm = (wave >> 1) * 64, wn = (wave & 1) * 32;

    f32x4 acc[4][2];
    const f32x4 zz = {0.f, 0.f, 0.f, 0.f};
#pragma unroll
    for (int i = 0; i < 4; i++)
#pragma unroll
        for (int j = 0; j < 2; j++) acc[i][j] = zz;

    // A combine-staging: lane handles rows r0, r0+64; 8 cols at c8
    const int r0 = tid >> 2;             // 0..63
    const int c8 = (tid & 3) * 8;
    const int bB = rowBase >> 11;        // batch (scalar: 128 | 2048)
    const int n0 = (rowBase & (NN - 1)) + r0;

    // B staging (GLDS + swizzle)
    const int br = wave * 16 + (lane >> 2);
    const int sc = ((lane & 3) ^ ((lane >> 3) & 3)) * 8;
    const ushort_t* Bg0 = WoT + (size_t)(colBase + br) * D_MODEL + sc;
    const int segB = wave * 512;
    const int fcol = (quad ^ ((l16 >> 1) & 3)) * 8;

    uint4 a0c0, a0c1, a1c0, a1c1;
    float l00, l01, l10, l11;
    // prefetch A inputs for K-slice k0
#define PREFA(k0) { \
        const int h_ = (k0) >> 6; \
        const int d_ = ((k0) & 63) + c8; \
        const size_t t0_ = ((size_t)(bB * 16 + h_) << 11) + n0; \
        const size_t t1_ = t0_ + 64; \
        a0c0 = *(const uint4*)&Pnum[t0_ * 64 + d_]; \
        a0c1 = *(const uint4*)&Pnum[((size_t)NTASK + t0_) * 64 + d_]; \
        a1c0 = *(const uint4*)&Pnum[t1_ * 64 + d_]; \
        a1c1 = *(const uint4*)&Pnum[((size_t)NTASK + t1_) * 64 + d_]; \
        l00 = Pl[t0_]; l01 = Pl[NTASK + t0_]; \
        l10 = Pl[t1_]; l11 = Pl[NTASK + t1_]; \
    }

    PREFA(0);
    GLDS(Bg0, &Bs[0][segB]);

    for (int k0 = 0; k0 < D_MODEL; k0 += 32) {
        const int cur = (k0 >> 5) & 1, nxt = cur ^ 1;
        __syncthreads();     // prev-iter frag reads done; Bs[cur] GLDS drained

        // combine + stage A (two rows)
        {
            const float i0 = 1.f / (l00 + l01), w00 = l00 * i0, w01 = l01 * i0;
            const float i1 = 1.f / (l10 + l11), w10 = l10 * i1, w11 = l11 * i1;
            uint4 o0, o1;
            const uint_t* p0 = (const uint_t*)&a0c0;
            const uint_t* p1 = (const uint_t*)&a0c1;
            const uint_t* q0 = (const uint_t*)&a1c0;
            const uint_t* q1 = (const uint_t*)&a1c1;
            uint_t* po = (uint_t*)&o0;
            uint_t* qo = (uint_t*)&o1;
#pragma unroll
            for (int j = 0; j < 4; j++) {
                fp16x2 u = *(const fp16x2*)&p0[j];
                fp16x2 v = *(const fp16x2*)&p1[j];
                po[j] = pk2h(w00 * (float)u.x + w01 * (float)v.x,
                             w00 * (float)u.y + w01 * (float)v.y);
                fp16x2 s = *(const fp16x2*)&q0[j];
                fp16x2 r = *(const fp16x2*)&q1[j];
                qo[j] = pk2h(w10 * (float)s.x + w11 * (float)r.x,
                             w10 * (float)s.y + w11 * (float)r.y);
            }
            *(uint4*)&As[cur][r0 * 40 + c8]        = o0;
            *(uint4*)&As[cur][(r0 + 64) * 40 + c8] = o1;
        }
        __syncthreads();     // As[cur] visible to all waves

        if (k0 + 32 < D_MODEL) {
            GLDS(Bg0 + k0 + 32, &Bs[nxt][segB]);
            PREFA(k0 + 32);
        }

        h16x8 af[4], bf[2];
#pragma unroll
        for (int mt = 0; mt < 4; mt++)
            af[mt] = *(const h16x8*)&As[cur][(wm + mt * 16 + l16) * 40 + quad * 8];
#pragma unroll
        for (int nt = 0; nt < 2; nt++)
            bf[nt] = *(const h16x8*)&Bs[cur][(wn + nt * 16 + l16) * 32 + fcol];
#pragma unroll
        for (int mt = 0; mt < 4; mt++)
#pragma unroll
            for (int nt = 0; nt < 2; nt++)
                acc[mt][nt] = MFMAH(af[mt], bf[nt], acc[mt][nt]);
    }
#undef PREFA

#pragma unroll
    for (int mt = 0; mt < 4; mt++)
#pragma unroll
        for (int nt = 0; nt < 2; nt++) {
            const int row = rowBase + wm + mt * 16 + quad * 4;
            const int col = colBase + wn + nt * 16 + l16;
#pragma unroll
            for (int r = 0; r < 4; r++)
                C[(size_t)(row + r) * D_MODEL + col] = acc[mt][nt][r];
        }
}

// ---------------------------------------------------------------------------
extern "C" void kernel_launch(void* const* d_in, const int* in_sizes, int n_in,
                              void* d_out, int out_size, void* d_ws, size_t ws_size,
                              hipStream_t stream)
{
    const float* x    = (const float*)d_in[0];
    const float* cosp = (const float*)d_in[1];
    const float* sinp = (const float*)d_in[2];
    const float* Wq   = (const float*)d_in[3];
    const float* Wk   = (const float*)d_in[4];
    const float* Wv   = (const float*)d_in[5];
    const float* Wo   = (const float*)d_in[6];

    char* w = (char*)d_ws;
    ushort_t* xb     = (ushort_t*)w;                       w += (size_t)MROWS * D_MODEL * 2;
    ushort_t* WqkvT  = (ushort_t*)w;                       w += (size_t)QKVN * D_MODEL * 2;
    ushort_t* WoT    = (ushort_t*)w;                       w += (size_t)D_MODEL * D_MODEL * 2;
    ushort_t* QKVh   = (ushort_t*)w;                       w += (size_t)MROWS * QKVN * 2;
    ushort_t* Qbuf   = (ushort_t*)w;                       w += (size_t)MROWS * D_MODEL * 2;
    ushort_t* Kbuf   = (ushort_t*)w;                       w += (size_t)MROWS * KVDIM * 2;
    ushort_t* Vt     = (ushort_t*)w;                       w += (size_t)MROWS * KVDIM * 2;
    ushort_t* Pnum   = (ushort_t*)w;                       w += (size_t)NSPLIT * NTASK * 64 * 2;
    float*    Pl     = (float*)w;

    // --- fused prep (cast + 4 transposes): 1 dispatch
    prep_kernel<<<6656, 256, 0, stream>>>(x, Wq, Wk, Wv, Wo, xb, WqkvT, WoT);

    // --- fused QKV projection (f16 out)
    gemm_qkv<<<dim3(QKVN / 64, MROWS / 128), 256, 0, stream>>>(
        xb, WqkvT, QKVh, MROWS, QKVN, D_MODEL);

    // --- rope + relayout (Q,K), V transpose
    rope_kernel<<<(NQW + NKW) / 256, 256, 0, stream>>>(QKVh, cosp, sinp, Qbuf, Kbuf);
    vtrans_kernel<<<dim3(NN / 32, KVDIM / 32, BB), 256, 0, stream>>>(QKVh, Vt);

    // --- attention (split-K x2, normalized f16 partials)
    attn_mfma<<<dim3(NN / 256, NHEADS, BB * NSPLIT), 256, 0, stream>>>(
        Qbuf, Kbuf, Vt, Pnum, Pl);

    // --- output projection with fused combine (fp32 out)
    gemm_wo<<<dim3(D_MODEL / 64, MROWS / 128), 256, 0, stream>>>(
        Pnum, Pl, WoT, (float*)d_out);
}